// Round 12
// baseline (2977.987 us; speedup 1.0000x reference)
//
#include <hip/hip_runtime.h>

// ---------------- types & helpers ----------------
typedef float f32x4 __attribute__((ext_vector_type(4)));
typedef __bf16 bf16x8 __attribute__((ext_vector_type(8)));
typedef unsigned short us8 __attribute__((ext_vector_type(8)));

static __device__ __forceinline__ unsigned short f2bf(float f){
    unsigned int u = __builtin_bit_cast(unsigned int, f);
    u += 0x7fffu + ((u >> 16) & 1u);
    return (unsigned short)(u >> 16);
}
static __device__ __forceinline__ bf16x8 ldb8(const unsigned short* p){
    return __builtin_bit_cast(bf16x8, *(const us8*)p);
}
typedef __attribute__((address_space(1))) void gas_void;
typedef __attribute__((address_space(3))) void las_void;
static __device__ __forceinline__ void gload_lds16(const void* g, void* l){
    __builtin_amdgcn_global_load_lds((gas_void*)g, (las_void*)l, 16, 0, 0);
}
static __device__ __forceinline__ float siluf(float v){
    return v / (1.f + __expf(-v));
}

// ---------------- prep: silu(plug_c_ref) rows 0..511, zero pad rows 512..639 ----------------
__global__ __launch_bounds__(256) void silu_hist_k(const float* __restrict__ plug,
                                                   unsigned short* __restrict__ siluc){
    int i = blockIdx.x*256 + threadIdx.x;
    if (i < 512*1152){
        siluc[i] = f2bf(siluf(plug[i]));
    } else if (i < 640*1152){
        siluc[i] = 0;   // pad rows: safe A-tile overread for M=516 GEMMs
    }
}

// ---------------- timestep MLP stage 1 (split-K x4): hl = silu(emb @ t_w0 + b0) ----------------
__global__ __launch_bounds__(256) void cgen1_k(const float* __restrict__ noise,
    const float* __restrict__ t_w0, const float* __restrict__ t_b0,
    float* __restrict__ hl){
    __shared__ float emb[256];
    __shared__ float part[4][64];
    const int t = threadIdx.x;
    const int b = blockIdx.y;
    const int c = blockIdx.x*64 + (t & 63);
    const int kg = t >> 6;
    const float tv = noise[b];
    if (t < 128){
        float arg = tv * __expf(-0.07195578415606394f * (float)t);
        emb[t] = cosf(arg);
        emb[128 + t] = sinf(arg);
    }
    __syncthreads();
    float s = 0.f;
    #pragma unroll 4
    for (int j = kg*64; j < kg*64 + 64; j++) s += emb[j] * t_w0[j*1152 + c];
    part[kg][t & 63] = s;
    __syncthreads();
    if (t < 64){
        float v = part[0][t] + part[1][t] + part[2][t] + part[3][t] + t_b0[c];
        hl[b*1152 + c] = siluf(v);
    }
}

// ---------------- timestep MLP stage 2 (split-K x4): siluc[512+b] = silu(hl @ t_w2 + b2) ----------------
__global__ __launch_bounds__(256) void cgen2_k(const float* __restrict__ hl,
    const float* __restrict__ t_w2, const float* __restrict__ t_b2,
    unsigned short* __restrict__ siluc){
    __shared__ float h[1152];
    __shared__ float part[4][64];
    const int t = threadIdx.x;
    const int b = blockIdx.y;
    const int c = blockIdx.x*64 + (t & 63);
    const int kg = t >> 6;
    for (int j = t; j < 1152; j += 256) h[j] = hl[b*1152 + j];
    __syncthreads();
    float s = 0.f;
    #pragma unroll 4
    for (int j = kg*288; j < kg*288 + 288; j++) s += h[j] * t_w2[j*1152 + c];
    part[kg][t & 63] = s;
    __syncthreads();
    if (t < 64){
        float v = part[0][t] + part[1][t] + part[2][t] + part[3][t] + t_b2[c];
        siluc[(size_t)(512 + b)*1152 + c] = f2bf(siluf(v));
    }
}

// ---------------- prep: x0 = tile(concat(rawhist,x),36) + pos_embed ----------------
__global__ __launch_bounds__(256) void x0_k(const float* __restrict__ xg,
    const float* __restrict__ rh, const float* __restrict__ pe, float* __restrict__ x){
    int i4 = blockIdx.x*256 + threadIdx.x;          // float4 index
    if (i4 >= 1179648) return;                      // 4096*1152/4
    int m = i4 / 288;
    int c = (i4 - m*288) * 4;
    int pos = m & 1023, b = m >> 10;
    const float* src = (pos < 512) ? (rh + ((size_t)b*512 + pos)*32)
                                   : (xg + ((size_t)b*512 + (pos-512))*32);
    float4 sv = *(const float4*)(src + (c & 31));
    float4 pv = *(const float4*)(pe + (size_t)pos*1152 + c);
    float4 o; o.x = sv.x+pv.x; o.y = sv.y+pv.y; o.z = sv.z+pv.z; o.w = sv.w+pv.w;
    *(float4*)(x + (size_t)i4*4) = o;
}

// ---------------- 32x32 transpose-convert body ----------------
static __device__ __forceinline__ void tw32_body(const float* __restrict__ W, int Kd, int Nd,
                                                 unsigned short* __restrict__ Wt,
                                                 int n0, int k0, int t){
    __shared__ float tile[32][33];
    #pragma unroll
    for (int i = 0; i < 4; i++){
        int idx = t + 256*i;
        int kk = idx >> 5, nn = idx & 31;
        tile[kk][nn] = W[(size_t)(k0+kk)*Nd + n0+nn];
    }
    __syncthreads();
    #pragma unroll
    for (int i = 0; i < 4; i++){
        int idx = t + 256*i;
        int nn = idx >> 5, kk = idx & 31;
        Wt[(size_t)(n0+nn)*Kd + k0+kk] = f2bf(tile[kk][nn]);
    }
}

__global__ __launch_bounds__(256) void tw_k(const float* __restrict__ W, int Kd, int Nd,
                                            unsigned short* __restrict__ Wt){
    tw32_body(W, Kd, Nd, Wt, blockIdx.x*32, blockIdx.y*32, threadIdx.x);
}

// ---------------- all 7 layers' ada weights upfront: 7 x 216x36 = 54432 tiles ----------------
__global__ __launch_bounds__(256) void twada7_k(const float* __restrict__ adaw,
                                                unsigned short* __restrict__ wta){
    int bid = blockIdx.x;
    const int l = bid / 7776;
    int local = bid - l*7776;                       // 216 x 36 tiles of 32x32
    const float* W = adaw + (size_t)l*7962624ul;    // 1152x6912 f32
    unsigned short* Wt = wta + (size_t)l*7962624ul; // 6912x1152 bf16
    tw32_body(W, 1152, 6912, Wt, (local % 216)*32, (local / 216)*32, threadIdx.x);
}

// ---------------- per-layer transpose of qkv/proj/fc1/fc2 ----------------
// tiles: qkv 108x36=3888 | proj 36x36=1296 | fc1 144x36=5184 | fc2 36x144=5184  (= 15552)
__global__ __launch_bounds__(256) void tw4_k(const float* __restrict__ w1,
    const float* __restrict__ w2, const float* __restrict__ w3, const float* __restrict__ w4,
    unsigned short* __restrict__ wt){
    const int cum[4]  = {3888, 5184, 10368, 15552};
    const int kds[4]  = {1152, 1152, 1152, 4608};
    const int nds[4]  = {3456, 1152, 4608, 1152};
    const size_t dof[4] = {7962624ul, 11943936ul, 13271040ul, 18579456ul};
    int bid = blockIdx.x;
    int w = (bid < cum[1]) ? ((bid < cum[0]) ? 0 : 1) : ((bid < cum[2]) ? 2 : 3);
    int local = bid - (w ? cum[w-1] : 0);
    const float* W = (w==0)?w1:(w==1)?w2:(w==2)?w3:w4;
    const int Kd = kds[w], Nd = nds[w];
    const int ntx = Nd >> 5;
    tw32_body(W, Kd, Nd, wt + dof[w], (local % ntx)*32, (local / ntx)*32, threadIdx.x);
}

// ---------------- LN (no affine) + modulate -> bf16 ----------------
__global__ __launch_bounds__(256) void ln_mod_k(const float* __restrict__ x,
    const float* __restrict__ modb, int mld, int ofs, unsigned short* __restrict__ y){
    const int m = blockIdx.x, t = threadIdx.x;
    const int lane = t & 63, wv = t >> 6;
    const float* xr = x + (size_t)m*1152;
    float4 v0 = ((const float4*)xr)[t];
    float4 v1 = {0.f,0.f,0.f,0.f};
    bool h2 = (t < 32);
    if (h2) v1 = ((const float4*)xr)[256 + t];
    float s = v0.x+v0.y+v0.z+v0.w + v1.x+v1.y+v1.z+v1.w;
    float q = v0.x*v0.x+v0.y*v0.y+v0.z*v0.z+v0.w*v0.w
            + v1.x*v1.x+v1.y*v1.y+v1.z*v1.z+v1.w*v1.w;
    #pragma unroll
    for (int o = 32; o; o >>= 1){ s += __shfl_xor(s,o); q += __shfl_xor(q,o); }
    __shared__ float red[8];
    if (lane == 0){ red[wv] = s; red[4+wv] = q; }
    __syncthreads();
    s = red[0]+red[1]+red[2]+red[3];
    q = red[4]+red[5]+red[6]+red[7];
    const float mean = s * (1.f/1152.f);
    const float var  = q * (1.f/1152.f) - mean*mean;
    const float rstd = rsqrtf(var + 1e-6f);
    const int pos = m & 1023, bb = m >> 10;
    const int mrow = (pos < 512) ? pos : (512 + bb);
    const float* sh = modb + (size_t)mrow*mld + ofs;
    const float* sc = sh + 1152;
    {
        int c = t*4;
        float4 shv = *(const float4*)(sh + c);
        float4 scv = *(const float4*)(sc + c);
        ushort4 o4;
        o4.x = f2bf((v0.x-mean)*rstd*(1.f+scv.x) + shv.x);
        o4.y = f2bf((v0.y-mean)*rstd*(1.f+scv.y) + shv.y);
        o4.z = f2bf((v0.z-mean)*rstd*(1.f+scv.z) + shv.z);
        o4.w = f2bf((v0.w-mean)*rstd*(1.f+scv.w) + shv.w);
        *(ushort4*)(y + (size_t)m*1152 + c) = o4;
    }
    if (h2){
        int c = 1024 + t*4;
        float4 shv = *(const float4*)(sh + c);
        float4 scv = *(const float4*)(sc + c);
        ushort4 o4;
        o4.x = f2bf((v1.x-mean)*rstd*(1.f+scv.x) + shv.x);
        o4.y = f2bf((v1.y-mean)*rstd*(1.f+scv.y) + shv.y);
        o4.z = f2bf((v1.z-mean)*rstd*(1.f+scv.z) + shv.z);
        o4.w = f2bf((v1.w-mean)*rstd*(1.f+scv.w) + shv.w);
        *(ushort4*)(y + (size_t)m*1152 + c) = o4;
    }
}

// ---------------- GEMM (m97 structure): out = epi(A(bf16,MxK) @ Wt^T + bias) ----------------
// EPI: 0 = bf16 store, 1 = gelu->bf16, 2 = f32 store (guard row<M), 3 = x += gate*(v)
// EPI=2 supports grid.z batching: B/bias/outf advance by bzs/biaszs/ozs per z.
template<int EPI>
__global__ __launch_bounds__(256,2)
void gemm2_k(const unsigned short* __restrict__ A, int lda,
             const unsigned short* __restrict__ B, int ldb,
             const float* __restrict__ bias,
             unsigned short* __restrict__ outb, float* __restrict__ outf, int ldo,
             int M, int K,
             float* __restrict__ xres,
             const float* __restrict__ modb, int mld, int gofs,
             size_t bzs, size_t biaszs, size_t ozs){
    if (EPI == 2){
        const size_t zz = blockIdx.z;
        B    += zz * bzs;
        bias += zz * biaszs;
        outf += zz * ozs;
    }
    __shared__ unsigned short Alds[128*32];
    __shared__ unsigned short Blds[128*32];
    const int tid  = threadIdx.x;
    const int lane = tid & 63;
    const int wv   = tid >> 6;
    const int wr   = wv >> 1, wc = wv & 1;
    const int m0 = blockIdx.x * 128;
    const int n0 = blockIdx.y * 128;

    const int r0 = (wv*2 + 0)*16 + (lane >> 2);
    const int r1 = (wv*2 + 1)*16 + (lane >> 2);
    const unsigned short* ag0 = A + (size_t)(m0 + r0)*lda + (lane & 3)*8;
    const unsigned short* ag1 = A + (size_t)(m0 + r1)*lda + (lane & 3)*8;
    const unsigned short* bg0 = B + (size_t)(n0 + r0)*ldb + (lane & 3)*8;
    const unsigned short* bg1 = B + (size_t)(n0 + r1)*ldb + (lane & 3)*8;
    unsigned short* al0 = &Alds[(wv*2 + 0)*512];
    unsigned short* al1 = &Alds[(wv*2 + 1)*512];
    unsigned short* bl0 = &Blds[(wv*2 + 0)*512];
    unsigned short* bl1 = &Blds[(wv*2 + 1)*512];

    f32x4 acc[4][4];
    #pragma unroll
    for (int i = 0; i < 4; i++)
        #pragma unroll
        for (int j = 0; j < 4; j++){ f32x4 z = {0.f,0.f,0.f,0.f}; acc[i][j] = z; }

    for (int ks = 0; ks < K; ks += 32){
        if (ks) __syncthreads();
        gload_lds16((const void*)ag0, (void*)al0);
        gload_lds16((const void*)ag1, (void*)al1);
        gload_lds16((const void*)bg0, (void*)bl0);
        gload_lds16((const void*)bg1, (void*)bl1);
        ag0 += 32; ag1 += 32; bg0 += 32; bg1 += 32;
        __syncthreads();
        bf16x8 af[4], bfm[4];
        #pragma unroll
        for (int mt = 0; mt < 4; mt++)
            af[mt] = ldb8(&Alds[(wr*64 + mt*16 + (lane&15))*32 + (lane>>4)*8]);
        #pragma unroll
        for (int nt = 0; nt < 4; nt++)
            bfm[nt] = ldb8(&Blds[(wc*64 + nt*16 + (lane&15))*32 + (lane>>4)*8]);
        #pragma unroll
        for (int mt = 0; mt < 4; mt++)
            #pragma unroll
            for (int nt = 0; nt < 4; nt++)
                acc[mt][nt] = __builtin_amdgcn_mfma_f32_16x16x32_bf16(af[mt], bfm[nt], acc[mt][nt], 0,0,0);
    }

    const int cb = n0 + wc*64;
    const int rb = m0 + wr*64;
    #pragma unroll
    for (int nt = 0; nt < 4; nt++){
        int col = cb + nt*16 + (lane & 15);
        float bn = bias[col];
        #pragma unroll
        for (int mt = 0; mt < 4; mt++){
            #pragma unroll
            for (int i = 0; i < 4; i++){
                int row = rb + mt*16 + (lane>>4)*4 + i;
                float v = acc[mt][nt][i] + bn;
                if (EPI == 0){
                    outb[(size_t)row*ldo + col] = f2bf(v);
                } else if (EPI == 1){
                    float z = 0.7978845608f*(v + 0.044715f*v*v*v);
                    float e = __expf(-2.f*fabsf(z));
                    float th = (1.f - e)/(1.f + e);
                    th = (z >= 0.f) ? th : -th;
                    outb[(size_t)row*ldo + col] = f2bf(0.5f*v*(1.f + th));
                } else if (EPI == 2){
                    if (row < M) outf[(size_t)row*ldo + col] = v;
                } else {
                    int pos = row & 1023, bb2 = row >> 10;
                    int mrow = (pos < 512) ? pos : (512 + bb2);
                    float g = modb[(size_t)mrow*mld + gofs + col];
                    xres[(size_t)row*1152 + col] += g * v;
                }
            }
        }
    }
}

// ---------------- flash attention v6: exp2-domain softmax + defer-max (T13) ----------------
__global__ __launch_bounds__(512)
void attn6_k(const unsigned short* __restrict__ qkv, unsigned short* __restrict__ o){
    __shared__ unsigned short Kl[128*104];    // 26.0 KB
    __shared__ unsigned short Vt[80*136];     // 21.25 KB  [d][kv], row 72 = ones
    __shared__ unsigned short Pl[8][16*40];   // 10 KB
    const int tid  = threadIdx.x;
    const int lane = tid & 63;
    const int w    = tid >> 6;
    const int bid  = blockIdx.x;
    const int qb   = 7 - (bid >> 6);          // heavy blocks first
    const int bh   = bid & 63;
    const int h = bh & 15, b = bh >> 4;
    const size_t base = (size_t)b*1024*3456;
    const int qcol = h*72, kcol = 1152 + h*72, vcol = 2304 + h*72;

    for (int idx = tid; idx < 2048; idx += 512){
        int r = idx >> 4, cw = idx & 15;
        ((unsigned int*)Kl)[r*52 + 36 + cw] = 0u;
    }
    if (tid < 544){
        int r = tid/68;
        ((unsigned int*)Vt)[(72+r)*68 + (tid - r*68)] = (r == 0) ? 0x3F803F80u : 0u;
    }

    bf16x8 qreg[3];
    const int q0 = qb*128 + w*16;
    {
        bf16x8 z8 = {};
        const unsigned short* qp = qkv + base + (size_t)(q0 + (lane&15))*3456 + qcol;
        const int off = (lane>>4)*8;
        qreg[0] = ldb8(qp + off);
        qreg[1] = ldb8(qp + 32 + off);
        qreg[2] = (lane < 16) ? ldb8(qp + 64) : z8;
    }

    float mi[4];
    f32x4 oa[5];
    #pragma unroll
    for (int i = 0; i < 4; i++) mi[i] = -INFINITY;
    #pragma unroll
    for (int d = 0; d < 5; d++){ f32x4 z = {0.f,0.f,0.f,0.f}; oa[d] = z; }

    const int nS = qb + 1;
    // log2-domain softmax: fold log2(e) into the scale; all exps become exp2f (1 v_exp each)
    const float qsc = 0.11785113019775793f * 1.4426950408889634f;

    for (int S = 0; S < nS; S++){
        const int kvS = S*128;
        __syncthreads();
        for (int ch = tid; ch < 2304; ch += 512){
            int r = ch/18, d4 = (ch - r*18)*4;
            *(ushort4*)&Kl[r*104 + d4] =
                *(const ushort4*)(qkv + base + (size_t)(kvS + r)*3456 + kcol + d4);
        }
        for (int ch = tid; ch < 1152; ch += 512){
            int rp = ch & 63, d4 = (ch >> 6)*4;
            const unsigned short* vp = qkv + base + (size_t)(kvS + 2*rp)*3456 + vcol + d4;
            ushort4 v0 = *(const ushort4*)vp;
            ushort4 v1 = *(const ushort4*)(vp + 3456);
            *(ushort2*)&Vt[(d4+0)*136 + 2*rp] = make_ushort2(v0.x, v1.x);
            *(ushort2*)&Vt[(d4+1)*136 + 2*rp] = make_ushort2(v0.y, v1.y);
            *(ushort2*)&Vt[(d4+2)*136 + 2*rp] = make_ushort2(v0.z, v1.z);
            *(ushort2*)&Vt[(d4+3)*136 + 2*rp] = make_ushort2(v0.w, v1.w);
        }
        __syncthreads();

        for (int sub = 0; sub < 4; sub++){
            const int kvb = kvS + sub*32;
            if (kvb > q0 + 15) break;
            f32x4 s0 = {0.f,0.f,0.f,0.f}, s1 = {0.f,0.f,0.f,0.f};
            __builtin_amdgcn_s_setprio(1);
            #pragma unroll
            for (int st = 0; st < 3; st++){
                bf16x8 k0 = ldb8(&Kl[(sub*32 + (lane&15))*104 + (lane>>4)*8 + st*32]);
                bf16x8 k1 = ldb8(&Kl[(sub*32 + 16 + (lane&15))*104 + (lane>>4)*8 + st*32]);
                s0 = __builtin_amdgcn_mfma_f32_16x16x32_bf16(qreg[st], k0, s0, 0,0,0);
                s1 = __builtin_amdgcn_mfma_f32_16x16x32_bf16(qreg[st], k1, s1, 0,0,0);
            }
            __builtin_amdgcn_s_setprio(0);
            const bool domask = (kvb + 31 > q0);
            float p0[4], p1[4];
            #pragma unroll
            for (int i = 0; i < 4; i++){
                float a = s0[i]*qsc, c = s1[i]*qsc;
                if (domask){
                    int r = q0 + (lane>>4)*4 + i;
                    if (kvb + (lane&15) > r) a = -1e30f;
                    if (kvb + 16 + (lane&15) > r) c = -1e30f;
                }
                float pm = fmaxf(a, c);
                #pragma unroll
                for (int off = 1; off < 16; off <<= 1) pm = fmaxf(pm, __shfl_xor(pm, off));
                // defer-max (T13, log2 domain): rescale only when max grows >12 (P <= 2^12)
                if (pm > mi[i] + 12.f){
                    float f = exp2f(mi[i] - pm);   // -inf first tile -> 0
                    mi[i] = pm;
                    #pragma unroll
                    for (int d = 0; d < 5; d++) oa[d][i] *= f;
                }
                p0[i] = exp2f(a - mi[i]);
                p1[i] = exp2f(c - mi[i]);
            }
            unsigned short* Pw = Pl[w];
            #pragma unroll
            for (int i = 0; i < 4; i++){
                int r = (lane>>4)*4 + i;
                Pw[r*40 + (lane&15)]      = f2bf(p0[i]);
                Pw[r*40 + 16 + (lane&15)] = f2bf(p1[i]);
            }
            bf16x8 pa = ldb8(&Pw[(lane&15)*40 + (lane>>4)*8]);
            __builtin_amdgcn_s_setprio(1);
            #pragma unroll
            for (int d = 0; d < 5; d++){
                bf16x8 bv = ldb8(&Vt[(d*16 + (lane&15))*136 + sub*32 + (lane>>4)*8]);
                oa[d] = __builtin_amdgcn_mfma_f32_16x16x32_bf16(pa, bv, oa[d], 0,0,0);
            }
            __builtin_amdgcn_s_setprio(0);
        }
    }
    // epilogue: li (sum of P) lives at output-col 72 = frag d=4, col 8
    #pragma unroll
    for (int i = 0; i < 4; i++){
        float li = __shfl(oa[4][i], (lane & 48) | 8);
        float inv = 1.f / li;
        size_t row = (size_t)b*1024 + q0 + (lane>>4)*4 + i;
        #pragma unroll
        for (int d = 0; d < 5; d++){
            int c = d*16 + (lane & 15);
            if (c < 72) o[row*1152 + h*72 + c] = f2bf(oa[d][i]*inv);
        }
    }
}

// ---------------- final: out = modulate(x, sh, sc) @ fin_w + fin_b (GEN rows) ----------------
__global__ __launch_bounds__(256) void final_k(const float* __restrict__ x,
    const float* __restrict__ modf, const float* __restrict__ finw,
    const float* __restrict__ finb, float* __restrict__ outp){
    __shared__ float yl[1152];
    __shared__ float ps[8][32];
    const int t = threadIdx.x;
    for (int r = 0; r < 8; r++){
        int gr = blockIdx.x*8 + r;
        int b = gr >> 9, p = gr & 511;
        size_t m = (size_t)b*1024 + 512 + p;
        int mrow = 512 + b;
        const float* xr = x + m*1152;
        const float* md = modf + (size_t)mrow*2304;
        for (int c = t; c < 1152; c += 256)
            yl[c] = xr[c]*(1.f + md[1152 + c]) + md[c];
        __syncthreads();
        int j = t & 31, g = t >> 5;
        float s = 0.f;
        for (int c = g*144; c < g*144 + 144; c++) s += yl[c]*finw[c*32 + j];
        ps[g][j] = s;
        __syncthreads();
        if (t < 32){
            float acc = finb[j];
            #pragma unroll
            for (int gg = 0; gg < 8; gg++) acc += ps[gg][j];
            outp[((size_t)b*512 + p)*32 + j] = acc;
        }
        __syncthreads();
    }
}

// ---------------- host launch ----------------
extern "C" void kernel_launch(void* const* d_in, const int* in_sizes, int n_in,
                              void* d_out, int out_size, void* d_ws, size_t ws_size,
                              hipStream_t stream){
    const float* xin   = (const float*)d_in[0];
    const float* noise = (const float*)d_in[1];
    const float* rawh  = (const float*)d_in[2];
    const float* pose  = (const float*)d_in[4];
    const float* plug  = (const float*)d_in[5];
    const float* t_w0  = (const float*)d_in[6];
    const float* t_b0  = (const float*)d_in[7];
    const float* t_w2  = (const float*)d_in[8];
    const float* t_b2  = (const float*)d_in[9];
    const float* qkvw  = (const float*)d_in[10];
    const float* qkvb  = (const float*)d_in[11];
    const float* projw = (const float*)d_in[12];
    const float* projb = (const float*)d_in[13];
    const float* fc1w  = (const float*)d_in[14];
    const float* fc1b  = (const float*)d_in[15];
    const float* fc2w  = (const float*)d_in[16];
    const float* fc2b  = (const float*)d_in[17];
    const float* adaw  = (const float*)d_in[18];
    const float* adab  = (const float*)d_in[19];
    const float* finaw = (const float*)d_in[20];
    const float* finab = (const float*)d_in[21];
    const float* finw  = (const float*)d_in[22];
    const float* finb  = (const float*)d_in[23];

    char* ws = (char*)d_ws;
    float*          xbuf  = (float*)(ws + 0);                      // 4096x1152 f32   (18.87 MB)
    unsigned short* ybuf  = (unsigned short*)(ws + 18874368);      // 4096x1152 bf16  (9.44 MB)
    unsigned short* qh    = (unsigned short*)(ws + 28311552);      // 4096x4608 bf16  (37.75 MB)
    unsigned short* siluc = (unsigned short*)(ws + 66060288);      // 640x1152 bf16   (1.47 MB)
    float*          modb7 = (float*)(ws + 67534848);               // 7x516x6912 f32  (99.86 MB)
    unsigned short* wt    = (unsigned short*)(ws + 167399424);     // per-layer slab  (47.78 MB)
    unsigned short* wta   = (unsigned short*)(ws + 215175168);     // 7x6912x1152 bf16 (111.48 MB)
    unsigned short* wtf   = (unsigned short*)(ws + 326651904);     // final ada       (5.31 MB)
    float*          hl    = (float*)qh;

    const bool merged = (ws_size >= 331960320ul);

    silu_hist_k<<<2880,256,0,stream>>>(plug, siluc);
    cgen1_k<<<dim3(18,4),256,0,stream>>>(noise, t_w0, t_b0, hl);
    cgen2_k<<<dim3(18,4),256,0,stream>>>(hl, t_w2, t_b2, siluc);
    x0_k<<<4608,256,0,stream>>>(xin, rawh, pose, xbuf);

    if (merged){
        twada7_k<<<54432,256,0,stream>>>(adaw, wta);
        gemm2_k<2><<<dim3(5,54,7),256,0,stream>>>(siluc,1152, wta,1152, adab,
            nullptr, modb7, 6912, 516, 1152, nullptr, nullptr, 0, 0,
            7962624ul, 6912ul, 3566592ul);
    }

    unsigned short* wt_qkv = merged ? wt +  7962624 : wt;
    unsigned short* wt_prj = merged ? wt + 11943936 : wt;
    unsigned short* wt_fc1 = merged ? wt + 13271040 : wt;
    unsigned short* wt_fc2 = merged ? wt + 18579456 : wt;

    for (int l = 0; l < 7; l++){
        float* mptr = merged ? modb7 + (size_t)l*3566592ul : modb7;
        if (merged){
            tw4_k<<<15552,256,0,stream>>>(qkvw + (size_t)l*1152*3456,
                projw + (size_t)l*1152*1152, fc1w + (size_t)l*1152*4608,
                fc2w + (size_t)l*4608*1152, wt);
        } else {
            tw_k<<<dim3(216,36),256,0,stream>>>(adaw + (size_t)l*1152*6912, 1152, 6912, wt);
            gemm2_k<2><<<dim3(5,54),256,0,stream>>>(siluc,1152, wt,1152, adab + (size_t)l*6912,
                nullptr, modb7, 6912, 516, 1152, nullptr, nullptr, 0, 0, 0ul, 0ul, 0ul);
        }
        ln_mod_k<<<4096,256,0,stream>>>(xbuf, mptr, 6912, 0, ybuf);
        // qkv
        if (!merged) tw_k<<<dim3(108,36),256,0,stream>>>(qkvw + (size_t)l*1152*3456, 1152, 3456, wt);
        gemm2_k<0><<<dim3(32,27),256,0,stream>>>(ybuf,1152, wt_qkv,1152, qkvb + (size_t)l*3456,
            qh, nullptr, 3456, 4096, 1152, nullptr, nullptr, 0, 0, 0ul, 0ul, 0ul);
        attn6_k<<<512,512,0,stream>>>(qh, ybuf);
        // proj (+ gated residual into xbuf)
        if (!merged) tw_k<<<dim3(36,36),256,0,stream>>>(projw + (size_t)l*1152*1152, 1152, 1152, wt);
        gemm2_k<3><<<dim3(32,9),256,0,stream>>>(ybuf,1152, wt_prj,1152, projb + (size_t)l*1152,
            nullptr, nullptr, 1152, 4096, 1152, xbuf, mptr, 6912, 2304, 0ul, 0ul, 0ul);
        ln_mod_k<<<4096,256,0,stream>>>(xbuf, mptr, 6912, 3456, ybuf);
        // fc1 (gelu)
        if (!merged) tw_k<<<dim3(144,36),256,0,stream>>>(fc1w + (size_t)l*1152*4608, 1152, 4608, wt);
        gemm2_k<1><<<dim3(32,36),256,0,stream>>>(ybuf,1152, wt_fc1,1152, fc1b + (size_t)l*4608,
            qh, nullptr, 4608, 4096, 1152, nullptr, nullptr, 0, 0, 0ul, 0ul, 0ul);
        // fc2 (+ gated residual into xbuf)
        if (!merged) tw_k<<<dim3(36,144),256,0,stream>>>(fc2w + (size_t)l*4608*1152, 4608, 1152, wt);
        gemm2_k<3><<<dim3(32,9),256,0,stream>>>(qh,4608, wt_fc2,4608, fc2b + (size_t)l*1152,
            nullptr, nullptr, 1152, 4096, 4608, xbuf, mptr, 6912, 5760, 0ul, 0ul, 0ul);
    }
    // final adaLN + projection
    unsigned short* wfin = merged ? wtf : wt;
    tw_k<<<dim3(72,36),256,0,stream>>>(finaw, 1152, 2304, wfin);
    gemm2_k<2><<<dim3(5,18),256,0,stream>>>(siluc,1152, wfin,1152, finab,
        nullptr, modb7, 2304, 516, 1152, nullptr, nullptr, 0, 0, 0ul, 0ul, 0ul);
    final_k<<<256,256,0,stream>>>(xbuf, modb7, finw, finb, (float*)d_out);
}

// Round 13
// 2858.752 us; speedup vs baseline: 1.0417x; 1.0417x over previous
//
#include <hip/hip_runtime.h>

// ---------------- types & helpers ----------------
typedef float f32x4 __attribute__((ext_vector_type(4)));
typedef __bf16 bf16x8 __attribute__((ext_vector_type(8)));
typedef unsigned short us8 __attribute__((ext_vector_type(8)));

static __device__ __forceinline__ unsigned short f2bf(float f){
    unsigned int u = __builtin_bit_cast(unsigned int, f);
    u += 0x7fffu + ((u >> 16) & 1u);
    return (unsigned short)(u >> 16);
}
static __device__ __forceinline__ bf16x8 ldb8(const unsigned short* p){
    return __builtin_bit_cast(bf16x8, *(const us8*)p);
}
typedef __attribute__((address_space(1))) void gas_void;
typedef __attribute__((address_space(3))) void las_void;
static __device__ __forceinline__ void gload_lds16(const void* g, void* l){
    __builtin_amdgcn_global_load_lds((gas_void*)g, (las_void*)l, 16, 0, 0);
}
static __device__ __forceinline__ float siluf(float v){
    return v / (1.f + __expf(-v));
}

// ---------------- prep: silu(plug_c_ref) rows 0..511, zero pad rows 512..639 ----------------
__global__ __launch_bounds__(256) void silu_hist_k(const float* __restrict__ plug,
                                                   unsigned short* __restrict__ siluc){
    int i = blockIdx.x*256 + threadIdx.x;
    if (i < 512*1152){
        siluc[i] = f2bf(siluf(plug[i]));
    } else if (i < 640*1152){
        siluc[i] = 0;   // pad rows: safe A-tile overread for M=516 GEMMs
    }
}

// ---------------- timestep MLP stage 1 (split-K x4): hl = silu(emb @ t_w0 + b0) ----------------
__global__ __launch_bounds__(256) void cgen1_k(const float* __restrict__ noise,
    const float* __restrict__ t_w0, const float* __restrict__ t_b0,
    float* __restrict__ hl){
    __shared__ float emb[256];
    __shared__ float part[4][64];
    const int t = threadIdx.x;
    const int b = blockIdx.y;
    const int c = blockIdx.x*64 + (t & 63);
    const int kg = t >> 6;
    const float tv = noise[b];
    if (t < 128){
        float arg = tv * __expf(-0.07195578415606394f * (float)t);
        emb[t] = cosf(arg);
        emb[128 + t] = sinf(arg);
    }
    __syncthreads();
    float s = 0.f;
    #pragma unroll 4
    for (int j = kg*64; j < kg*64 + 64; j++) s += emb[j] * t_w0[j*1152 + c];
    part[kg][t & 63] = s;
    __syncthreads();
    if (t < 64){
        float v = part[0][t] + part[1][t] + part[2][t] + part[3][t] + t_b0[c];
        hl[b*1152 + c] = siluf(v);
    }
}

// ---------------- timestep MLP stage 2 (split-K x4): siluc[512+b] = silu(hl @ t_w2 + b2) ----------------
__global__ __launch_bounds__(256) void cgen2_k(const float* __restrict__ hl,
    const float* __restrict__ t_w2, const float* __restrict__ t_b2,
    unsigned short* __restrict__ siluc){
    __shared__ float h[1152];
    __shared__ float part[4][64];
    const int t = threadIdx.x;
    const int b = blockIdx.y;
    const int c = blockIdx.x*64 + (t & 63);
    const int kg = t >> 6;
    for (int j = t; j < 1152; j += 256) h[j] = hl[b*1152 + j];
    __syncthreads();
    float s = 0.f;
    #pragma unroll 4
    for (int j = kg*288; j < kg*288 + 288; j++) s += h[j] * t_w2[j*1152 + c];
    part[kg][t & 63] = s;
    __syncthreads();
    if (t < 64){
        float v = part[0][t] + part[1][t] + part[2][t] + part[3][t] + t_b2[c];
        siluc[(size_t)(512 + b)*1152 + c] = f2bf(siluf(v));
    }
}

// ---------------- prep: x0 = tile(concat(rawhist,x),36) + pos_embed ----------------
__global__ __launch_bounds__(256) void x0_k(const float* __restrict__ xg,
    const float* __restrict__ rh, const float* __restrict__ pe, float* __restrict__ x){
    int i4 = blockIdx.x*256 + threadIdx.x;          // float4 index
    if (i4 >= 1179648) return;                      // 4096*1152/4
    int m = i4 / 288;
    int c = (i4 - m*288) * 4;
    int pos = m & 1023, b = m >> 10;
    const float* src = (pos < 512) ? (rh + ((size_t)b*512 + pos)*32)
                                   : (xg + ((size_t)b*512 + (pos-512))*32);
    float4 sv = *(const float4*)(src + (c & 31));
    float4 pv = *(const float4*)(pe + (size_t)pos*1152 + c);
    float4 o; o.x = sv.x+pv.x; o.y = sv.y+pv.y; o.z = sv.z+pv.z; o.w = sv.w+pv.w;
    *(float4*)(x + (size_t)i4*4) = o;
}

// ---------------- 32x32 transpose-convert body ----------------
static __device__ __forceinline__ void tw32_body(const float* __restrict__ W, int Kd, int Nd,
                                                 unsigned short* __restrict__ Wt,
                                                 int n0, int k0, int t){
    __shared__ float tile[32][33];
    #pragma unroll
    for (int i = 0; i < 4; i++){
        int idx = t + 256*i;
        int kk = idx >> 5, nn = idx & 31;
        tile[kk][nn] = W[(size_t)(k0+kk)*Nd + n0+nn];
    }
    __syncthreads();
    #pragma unroll
    for (int i = 0; i < 4; i++){
        int idx = t + 256*i;
        int nn = idx >> 5, kk = idx & 31;
        Wt[(size_t)(n0+nn)*Kd + k0+kk] = f2bf(tile[kk][nn]);
    }
}

__global__ __launch_bounds__(256) void tw_k(const float* __restrict__ W, int Kd, int Nd,
                                            unsigned short* __restrict__ Wt){
    tw32_body(W, Kd, Nd, Wt, blockIdx.x*32, blockIdx.y*32, threadIdx.x);
}

// ---------------- all 7 layers' ada weights upfront: 7 x 216x36 = 54432 tiles ----------------
__global__ __launch_bounds__(256) void twada7_k(const float* __restrict__ adaw,
                                                unsigned short* __restrict__ wta){
    int bid = blockIdx.x;
    const int l = bid / 7776;
    int local = bid - l*7776;                       // 216 x 36 tiles of 32x32
    const float* W = adaw + (size_t)l*7962624ul;    // 1152x6912 f32
    unsigned short* Wt = wta + (size_t)l*7962624ul; // 6912x1152 bf16
    tw32_body(W, 1152, 6912, Wt, (local % 216)*32, (local / 216)*32, threadIdx.x);
}

// ---------------- per-layer transpose of qkv/proj/fc1/fc2 ----------------
// tiles: qkv 108x36=3888 | proj 36x36=1296 | fc1 144x36=5184 | fc2 36x144=5184  (= 15552)
__global__ __launch_bounds__(256) void tw4_k(const float* __restrict__ w1,
    const float* __restrict__ w2, const float* __restrict__ w3, const float* __restrict__ w4,
    unsigned short* __restrict__ wt){
    const int cum[4]  = {3888, 5184, 10368, 15552};
    const int kds[4]  = {1152, 1152, 1152, 4608};
    const int nds[4]  = {3456, 1152, 4608, 1152};
    const size_t dof[4] = {7962624ul, 11943936ul, 13271040ul, 18579456ul};
    int bid = blockIdx.x;
    int w = (bid < cum[1]) ? ((bid < cum[0]) ? 0 : 1) : ((bid < cum[2]) ? 2 : 3);
    int local = bid - (w ? cum[w-1] : 0);
    const float* W = (w==0)?w1:(w==1)?w2:(w==2)?w3:w4;
    const int Kd = kds[w], Nd = nds[w];
    const int ntx = Nd >> 5;
    tw32_body(W, Kd, Nd, wt + dof[w], (local % ntx)*32, (local / ntx)*32, threadIdx.x);
}

// ---------------- LN (no affine) + modulate -> bf16 ----------------
// genonly: grid 2048, rows b*1024 + 512 + p (GEN rows only)
__global__ __launch_bounds__(256) void ln_mod_k(const float* __restrict__ x,
    const float* __restrict__ modb, int mld, int ofs, unsigned short* __restrict__ y,
    int genonly){
    const int bx = blockIdx.x, t = threadIdx.x;
    const int m = genonly ? ((bx >> 9)*1024 + 512 + (bx & 511)) : bx;
    const int lane = t & 63, wv = t >> 6;
    const float* xr = x + (size_t)m*1152;
    float4 v0 = ((const float4*)xr)[t];
    float4 v1 = {0.f,0.f,0.f,0.f};
    bool h2 = (t < 32);
    if (h2) v1 = ((const float4*)xr)[256 + t];
    float s = v0.x+v0.y+v0.z+v0.w + v1.x+v1.y+v1.z+v1.w;
    float q = v0.x*v0.x+v0.y*v0.y+v0.z*v0.z+v0.w*v0.w
            + v1.x*v1.x+v1.y*v1.y+v1.z*v1.z+v1.w*v1.w;
    #pragma unroll
    for (int o = 32; o; o >>= 1){ s += __shfl_xor(s,o); q += __shfl_xor(q,o); }
    __shared__ float red[8];
    if (lane == 0){ red[wv] = s; red[4+wv] = q; }
    __syncthreads();
    s = red[0]+red[1]+red[2]+red[3];
    q = red[4]+red[5]+red[6]+red[7];
    const float mean = s * (1.f/1152.f);
    const float var  = q * (1.f/1152.f) - mean*mean;
    const float rstd = rsqrtf(var + 1e-6f);
    const int pos = m & 1023, bb = m >> 10;
    const int mrow = (pos < 512) ? pos : (512 + bb);
    const float* sh = modb + (size_t)mrow*mld + ofs;
    const float* sc = sh + 1152;
    {
        int c = t*4;
        float4 shv = *(const float4*)(sh + c);
        float4 scv = *(const float4*)(sc + c);
        ushort4 o4;
        o4.x = f2bf((v0.x-mean)*rstd*(1.f+scv.x) + shv.x);
        o4.y = f2bf((v0.y-mean)*rstd*(1.f+scv.y) + shv.y);
        o4.z = f2bf((v0.z-mean)*rstd*(1.f+scv.z) + shv.z);
        o4.w = f2bf((v0.w-mean)*rstd*(1.f+scv.w) + shv.w);
        *(ushort4*)(y + (size_t)m*1152 + c) = o4;
    }
    if (h2){
        int c = 1024 + t*4;
        float4 shv = *(const float4*)(sh + c);
        float4 scv = *(const float4*)(sc + c);
        ushort4 o4;
        o4.x = f2bf((v1.x-mean)*rstd*(1.f+scv.x) + shv.x);
        o4.y = f2bf((v1.y-mean)*rstd*(1.f+scv.y) + shv.y);
        o4.z = f2bf((v1.z-mean)*rstd*(1.f+scv.z) + shv.z);
        o4.w = f2bf((v1.w-mean)*rstd*(1.f+scv.w) + shv.w);
        *(ushort4*)(y + (size_t)m*1152 + c) = o4;
    }
}

// ---------------- GEMM (m97 structure): out = epi(A(bf16,MxK) @ Wt^T + bias) ----------------
// EPI: 0 = bf16 store, 1 = gelu->bf16, 2 = f32 store (guard row<M), 3 = x += gate*(v)
// genmap: M-tiles remapped to GEN rows: m-tile = batch*8 + 4 + (bx&3), bx in 0..15
template<int EPI>
__global__ __launch_bounds__(256,2)
void gemm2_k(const unsigned short* __restrict__ A, int lda,
             const unsigned short* __restrict__ B, int ldb,
             const float* __restrict__ bias,
             unsigned short* __restrict__ outb, float* __restrict__ outf, int ldo,
             int M, int K,
             float* __restrict__ xres,
             const float* __restrict__ modb, int mld, int gofs,
             int genmap){
    __shared__ unsigned short Alds[128*32];
    __shared__ unsigned short Blds[128*32];
    const int tid  = threadIdx.x;
    const int lane = tid & 63;
    const int wv   = tid >> 6;
    const int wr   = wv >> 1, wc = wv & 1;
    const int bx = blockIdx.x;
    const int m0 = (genmap ? ((bx >> 2)*8 + 4 + (bx & 3)) : bx) * 128;
    const int n0 = blockIdx.y * 128;

    const int r0 = (wv*2 + 0)*16 + (lane >> 2);
    const int r1 = (wv*2 + 1)*16 + (lane >> 2);
    const unsigned short* ag0 = A + (size_t)(m0 + r0)*lda + (lane & 3)*8;
    const unsigned short* ag1 = A + (size_t)(m0 + r1)*lda + (lane & 3)*8;
    const unsigned short* bg0 = B + (size_t)(n0 + r0)*ldb + (lane & 3)*8;
    const unsigned short* bg1 = B + (size_t)(n0 + r1)*ldb + (lane & 3)*8;
    unsigned short* al0 = &Alds[(wv*2 + 0)*512];
    unsigned short* al1 = &Alds[(wv*2 + 1)*512];
    unsigned short* bl0 = &Blds[(wv*2 + 0)*512];
    unsigned short* bl1 = &Blds[(wv*2 + 1)*512];

    f32x4 acc[4][4];
    #pragma unroll
    for (int i = 0; i < 4; i++)
        #pragma unroll
        for (int j = 0; j < 4; j++){ f32x4 z = {0.f,0.f,0.f,0.f}; acc[i][j] = z; }

    for (int ks = 0; ks < K; ks += 32){
        if (ks) __syncthreads();
        gload_lds16((const void*)ag0, (void*)al0);
        gload_lds16((const void*)ag1, (void*)al1);
        gload_lds16((const void*)bg0, (void*)bl0);
        gload_lds16((const void*)bg1, (void*)bl1);
        ag0 += 32; ag1 += 32; bg0 += 32; bg1 += 32;
        __syncthreads();
        bf16x8 af[4], bfm[4];
        #pragma unroll
        for (int mt = 0; mt < 4; mt++)
            af[mt] = ldb8(&Alds[(wr*64 + mt*16 + (lane&15))*32 + (lane>>4)*8]);
        #pragma unroll
        for (int nt = 0; nt < 4; nt++)
            bfm[nt] = ldb8(&Blds[(wc*64 + nt*16 + (lane&15))*32 + (lane>>4)*8]);
        #pragma unroll
        for (int mt = 0; mt < 4; mt++)
            #pragma unroll
            for (int nt = 0; nt < 4; nt++)
                acc[mt][nt] = __builtin_amdgcn_mfma_f32_16x16x32_bf16(af[mt], bfm[nt], acc[mt][nt], 0,0,0);
    }

    const int cb = n0 + wc*64;
    const int rb = m0 + wr*64;
    #pragma unroll
    for (int nt = 0; nt < 4; nt++){
        int col = cb + nt*16 + (lane & 15);
        float bn = bias[col];
        #pragma unroll
        for (int mt = 0; mt < 4; mt++){
            #pragma unroll
            for (int i = 0; i < 4; i++){
                int row = rb + mt*16 + (lane>>4)*4 + i;
                float v = acc[mt][nt][i] + bn;
                if (EPI == 0){
                    outb[(size_t)row*ldo + col] = f2bf(v);
                } else if (EPI == 1){
                    float z = 0.7978845608f*(v + 0.044715f*v*v*v);
                    float e = __expf(-2.f*fabsf(z));
                    float th = (1.f - e)/(1.f + e);
                    th = (z >= 0.f) ? th : -th;
                    outb[(size_t)row*ldo + col] = f2bf(0.5f*v*(1.f + th));
                } else if (EPI == 2){
                    if (row < M) outf[(size_t)row*ldo + col] = v;
                } else {
                    int pos = row & 1023, bb2 = row >> 10;
                    int mrow = (pos < 512) ? pos : (512 + bb2);
                    float g = modb[(size_t)mrow*mld + gofs + col];
                    xres[(size_t)row*1152 + col] += g * v;
                }
            }
        }
    }
}

// ---------------- batched ada GEMM with XCD panel swizzle ----------------
// grid 1920 x 1D. Panel p = z*54 + n (378 panels), m in 0..4.
// bid = (p%8) + 8*(m + 5*(p/8)): same-panel blocks 8 apart -> same XCD L2.
__global__ __launch_bounds__(256,2)
void gemm_ada_k(const unsigned short* __restrict__ A,
                const unsigned short* __restrict__ Wta,
                const float* __restrict__ adab,
                float* __restrict__ modb7){
    const int bid = blockIdx.x;
    const int r8 = bid & 7;
    const int t8 = bid >> 3;
    const int m  = t8 % 5;
    const int p  = (t8 / 5)*8 + r8;
    if (p >= 378) return;
    const int z = p / 54, n = p % 54;
    const unsigned short* B = Wta + (size_t)z*7962624ul;
    const float* bias = adab + (size_t)z*6912;
    float* outf = modb7 + (size_t)z*3566592ul;
    const int m0 = m * 128;
    const int n0 = n * 128;

    __shared__ unsigned short Alds[128*32];
    __shared__ unsigned short Blds[128*32];
    const int tid  = threadIdx.x;
    const int lane = tid & 63;
    const int wv   = tid >> 6;
    const int wr   = wv >> 1, wc = wv & 1;

    const int r0 = (wv*2 + 0)*16 + (lane >> 2);
    const int r1 = (wv*2 + 1)*16 + (lane >> 2);
    const unsigned short* ag0 = A + (size_t)(m0 + r0)*1152 + (lane & 3)*8;
    const unsigned short* ag1 = A + (size_t)(m0 + r1)*1152 + (lane & 3)*8;
    const unsigned short* bg0 = B + (size_t)(n0 + r0)*1152 + (lane & 3)*8;
    const unsigned short* bg1 = B + (size_t)(n0 + r1)*1152 + (lane & 3)*8;
    unsigned short* al0 = &Alds[(wv*2 + 0)*512];
    unsigned short* al1 = &Alds[(wv*2 + 1)*512];
    unsigned short* bl0 = &Blds[(wv*2 + 0)*512];
    unsigned short* bl1 = &Blds[(wv*2 + 1)*512];

    f32x4 acc[4][4];
    #pragma unroll
    for (int i = 0; i < 4; i++)
        #pragma unroll
        for (int j = 0; j < 4; j++){ f32x4 zv = {0.f,0.f,0.f,0.f}; acc[i][j] = zv; }

    for (int ks = 0; ks < 1152; ks += 32){
        if (ks) __syncthreads();
        gload_lds16((const void*)ag0, (void*)al0);
        gload_lds16((const void*)ag1, (void*)al1);
        gload_lds16((const void*)bg0, (void*)bl0);
        gload_lds16((const void*)bg1, (void*)bl1);
        ag0 += 32; ag1 += 32; bg0 += 32; bg1 += 32;
        __syncthreads();
        bf16x8 af[4], bfm[4];
        #pragma unroll
        for (int mt = 0; mt < 4; mt++)
            af[mt] = ldb8(&Alds[(wr*64 + mt*16 + (lane&15))*32 + (lane>>4)*8]);
        #pragma unroll
        for (int nt = 0; nt < 4; nt++)
            bfm[nt] = ldb8(&Blds[(wc*64 + nt*16 + (lane&15))*32 + (lane>>4)*8]);
        #pragma unroll
        for (int mt = 0; mt < 4; mt++)
            #pragma unroll
            for (int nt = 0; nt < 4; nt++)
                acc[mt][nt] = __builtin_amdgcn_mfma_f32_16x16x32_bf16(af[mt], bfm[nt], acc[mt][nt], 0,0,0);
    }

    const int cb = n0 + wc*64;
    const int rb = m0 + wr*64;
    #pragma unroll
    for (int nt = 0; nt < 4; nt++){
        int col = cb + nt*16 + (lane & 15);
        float bn = bias[col];
        #pragma unroll
        for (int mt = 0; mt < 4; mt++){
            #pragma unroll
            for (int i = 0; i < 4; i++){
                int row = rb + mt*16 + (lane>>4)*4 + i;
                float v = acc[mt][nt][i] + bn;
                if (row < 516) outf[(size_t)row*6912 + col] = v;
            }
        }
    }
}

// ---------------- flash attention v5: 8 waves x 16 q rows, 128-kv super-tiles ----------------
__global__ __launch_bounds__(512)
void attn5_k(const unsigned short* __restrict__ qkv, unsigned short* __restrict__ o){
    __shared__ unsigned short Kl[128*104];    // 26.0 KB
    __shared__ unsigned short Vt[80*136];     // 21.25 KB  [d][kv], row 72 = ones
    __shared__ unsigned short Pl[8][16*40];   // 10 KB
    const int tid  = threadIdx.x;
    const int lane = tid & 63;
    const int w    = tid >> 6;
    const int bid  = blockIdx.x;
    const int qb   = 7 - (bid >> 6);          // heavy blocks first; 256-block launch -> qb 4..7
    const int bh   = bid & 63;
    const int h = bh & 15, b = bh >> 4;
    const size_t base = (size_t)b*1024*3456;
    const int qcol = h*72, kcol = 1152 + h*72, vcol = 2304 + h*72;

    for (int idx = tid; idx < 2048; idx += 512){
        int r = idx >> 4, cw = idx & 15;
        ((unsigned int*)Kl)[r*52 + 36 + cw] = 0u;
    }
    if (tid < 544){
        int r = tid/68;
        ((unsigned int*)Vt)[(72+r)*68 + (tid - r*68)] = (r == 0) ? 0x3F803F80u : 0u;
    }

    bf16x8 qreg[3];
    const int q0 = qb*128 + w*16;
    {
        bf16x8 z8 = {};
        const unsigned short* qp = qkv + base + (size_t)(q0 + (lane&15))*3456 + qcol;
        const int off = (lane>>4)*8;
        qreg[0] = ldb8(qp + off);
        qreg[1] = ldb8(qp + 32 + off);
        qreg[2] = (lane < 16) ? ldb8(qp + 64) : z8;
    }

    float mi[4];
    f32x4 oa[5];
    #pragma unroll
    for (int i = 0; i < 4; i++) mi[i] = -INFINITY;
    #pragma unroll
    for (int d = 0; d < 5; d++){ f32x4 z = {0.f,0.f,0.f,0.f}; oa[d] = z; }

    const int nS = qb + 1;
    const float qsc = 0.11785113019775793f;

    for (int S = 0; S < nS; S++){
        const int kvS = S*128;
        __syncthreads();
        for (int ch = tid; ch < 2304; ch += 512){
            int r = ch/18, d4 = (ch - r*18)*4;
            *(ushort4*)&Kl[r*104 + d4] =
                *(const ushort4*)(qkv + base + (size_t)(kvS + r)*3456 + kcol + d4);
        }
        for (int ch = tid; ch < 1152; ch += 512){
            int rp = ch & 63, d4 = (ch >> 6)*4;
            const unsigned short* vp = qkv + base + (size_t)(kvS + 2*rp)*3456 + vcol + d4;
            ushort4 v0 = *(const ushort4*)vp;
            ushort4 v1 = *(const ushort4*)(vp + 3456);
            *(ushort2*)&Vt[(d4+0)*136 + 2*rp] = make_ushort2(v0.x, v1.x);
            *(ushort2*)&Vt[(d4+1)*136 + 2*rp] = make_ushort2(v0.y, v1.y);
            *(ushort2*)&Vt[(d4+2)*136 + 2*rp] = make_ushort2(v0.z, v1.z);
            *(ushort2*)&Vt[(d4+3)*136 + 2*rp] = make_ushort2(v0.w, v1.w);
        }
        __syncthreads();

        for (int sub = 0; sub < 4; sub++){
            const int kvb = kvS + sub*32;
            if (kvb > q0 + 15) break;
            f32x4 s0 = {0.f,0.f,0.f,0.f}, s1 = {0.f,0.f,0.f,0.f};
            __builtin_amdgcn_s_setprio(1);
            #pragma unroll
            for (int st = 0; st < 3; st++){
                bf16x8 k0 = ldb8(&Kl[(sub*32 + (lane&15))*104 + (lane>>4)*8 + st*32]);
                bf16x8 k1 = ldb8(&Kl[(sub*32 + 16 + (lane&15))*104 + (lane>>4)*8 + st*32]);
                s0 = __builtin_amdgcn_mfma_f32_16x16x32_bf16(qreg[st], k0, s0, 0,0,0);
                s1 = __builtin_amdgcn_mfma_f32_16x16x32_bf16(qreg[st], k1, s1, 0,0,0);
            }
            __builtin_amdgcn_s_setprio(0);
            const bool domask = (kvb + 31 > q0);
            float p0[4], p1[4];
            #pragma unroll
            for (int i = 0; i < 4; i++){
                float a = s0[i]*qsc, c = s1[i]*qsc;
                if (domask){
                    int r = q0 + (lane>>4)*4 + i;
                    if (kvb + (lane&15) > r) a = -1e30f;
                    if (kvb + 16 + (lane&15) > r) c = -1e30f;
                }
                float pm = fmaxf(a, c);
                #pragma unroll
                for (int off = 1; off < 16; off <<= 1) pm = fmaxf(pm, __shfl_xor(pm, off));
                float nm = fmaxf(mi[i], pm);
                float f = __expf(mi[i] - nm);
                mi[i] = nm;
                p0[i] = __expf(a - nm);
                p1[i] = __expf(c - nm);
                #pragma unroll
                for (int d = 0; d < 5; d++) oa[d][i] *= f;
            }
            unsigned short* Pw = Pl[w];
            #pragma unroll
            for (int i = 0; i < 4; i++){
                int r = (lane>>4)*4 + i;
                Pw[r*40 + (lane&15)]      = f2bf(p0[i]);
                Pw[r*40 + 16 + (lane&15)] = f2bf(p1[i]);
            }
            bf16x8 pa = ldb8(&Pw[(lane&15)*40 + (lane>>4)*8]);
            __builtin_amdgcn_s_setprio(1);
            #pragma unroll
            for (int d = 0; d < 5; d++){
                bf16x8 bv = ldb8(&Vt[(d*16 + (lane&15))*136 + sub*32 + (lane>>4)*8]);
                oa[d] = __builtin_amdgcn_mfma_f32_16x16x32_bf16(pa, bv, oa[d], 0,0,0);
            }
            __builtin_amdgcn_s_setprio(0);
        }
    }
    #pragma unroll
    for (int i = 0; i < 4; i++){
        float li = __shfl(oa[4][i], (lane & 48) | 8);
        float inv = 1.f / li;
        size_t row = (size_t)b*1024 + q0 + (lane>>4)*4 + i;
        #pragma unroll
        for (int d = 0; d < 5; d++){
            int c = d*16 + (lane & 15);
            if (c < 72) o[row*1152 + h*72 + c] = f2bf(oa[d][i]*inv);
        }
    }
}

// ---------------- final: out = modulate(x, sh, sc) @ fin_w + fin_b (GEN rows) ----------------
__global__ __launch_bounds__(256) void final_k(const float* __restrict__ x,
    const float* __restrict__ modf, const float* __restrict__ finw,
    const float* __restrict__ finb, float* __restrict__ outp){
    __shared__ float yl[1152];
    __shared__ float ps[8][32];
    const int t = threadIdx.x;
    for (int r = 0; r < 8; r++){
        int gr = blockIdx.x*8 + r;
        int b = gr >> 9, p = gr & 511;
        size_t m = (size_t)b*1024 + 512 + p;
        int mrow = 512 + b;
        const float* xr = x + m*1152;
        const float* md = modf + (size_t)mrow*2304;
        for (int c = t; c < 1152; c += 256)
            yl[c] = xr[c]*(1.f + md[1152 + c]) + md[c];
        __syncthreads();
        int j = t & 31, g = t >> 5;
        float s = 0.f;
        for (int c = g*144; c < g*144 + 144; c++) s += yl[c]*finw[c*32 + j];
        ps[g][j] = s;
        __syncthreads();
        if (t < 32){
            float acc = finb[j];
            #pragma unroll
            for (int gg = 0; gg < 8; gg++) acc += ps[gg][j];
            outp[((size_t)b*512 + p)*32 + j] = acc;
        }
        __syncthreads();
    }
}

// ---------------- host launch ----------------
extern "C" void kernel_launch(void* const* d_in, const int* in_sizes, int n_in,
                              void* d_out, int out_size, void* d_ws, size_t ws_size,
                              hipStream_t stream){
    const float* xin   = (const float*)d_in[0];
    const float* noise = (const float*)d_in[1];
    const float* rawh  = (const float*)d_in[2];
    const float* pose  = (const float*)d_in[4];
    const float* plug  = (const float*)d_in[5];
    const float* t_w0  = (const float*)d_in[6];
    const float* t_b0  = (const float*)d_in[7];
    const float* t_w2  = (const float*)d_in[8];
    const float* t_b2  = (const float*)d_in[9];
    const float* qkvw  = (const float*)d_in[10];
    const float* qkvb  = (const float*)d_in[11];
    const float* projw = (const float*)d_in[12];
    const float* projb = (const float*)d_in[13];
    const float* fc1w  = (const float*)d_in[14];
    const float* fc1b  = (const float*)d_in[15];
    const float* fc2w  = (const float*)d_in[16];
    const float* fc2b  = (const float*)d_in[17];
    const float* adaw  = (const float*)d_in[18];
    const float* adab  = (const float*)d_in[19];
    const float* finaw = (const float*)d_in[20];
    const float* finab = (const float*)d_in[21];
    const float* finw  = (const float*)d_in[22];
    const float* finb  = (const float*)d_in[23];

    char* ws = (char*)d_ws;
    float*          xbuf  = (float*)(ws + 0);                      // 4096x1152 f32   (18.87 MB)
    unsigned short* ybuf  = (unsigned short*)(ws + 18874368);      // 4096x1152 bf16  (9.44 MB)
    unsigned short* qh    = (unsigned short*)(ws + 28311552);      // 4096x4608 bf16  (37.75 MB)
    unsigned short* siluc = (unsigned short*)(ws + 66060288);      // 640x1152 bf16   (1.47 MB)
    float*          modb7 = (float*)(ws + 67534848);               // 7x516x6912 f32  (99.86 MB)
    unsigned short* wt    = (unsigned short*)(ws + 167399424);     // per-layer slab  (47.78 MB)
    unsigned short* wta   = (unsigned short*)(ws + 215175168);     // 7x6912x1152 bf16 (111.48 MB)
    unsigned short* wtf   = (unsigned short*)(ws + 326651904);     // final ada       (5.31 MB)
    float*          hl    = (float*)qh;

    const bool merged = (ws_size >= 331960320ul);

    silu_hist_k<<<2880,256,0,stream>>>(plug, siluc);
    cgen1_k<<<dim3(18,4),256,0,stream>>>(noise, t_w0, t_b0, hl);
    cgen2_k<<<dim3(18,4),256,0,stream>>>(hl, t_w2, t_b2, siluc);
    x0_k<<<4608,256,0,stream>>>(xin, rawh, pose, xbuf);

    if (merged){
        twada7_k<<<54432,256,0,stream>>>(adaw, wta);
        gemm_ada_k<<<1920,256,0,stream>>>(siluc, wta, adab, modb7);
    }

    unsigned short* wt_qkv = merged ? wt +  7962624 : wt;
    unsigned short* wt_prj = merged ? wt + 11943936 : wt;
    unsigned short* wt_fc1 = merged ? wt + 13271040 : wt;
    unsigned short* wt_fc2 = merged ? wt + 18579456 : wt;

    for (int l = 0; l < 7; l++){
        const bool last = (l == 6);
        const int gmap = last ? 1 : 0;
        float* mptr = merged ? modb7 + (size_t)l*3566592ul : modb7;
        if (merged){
            tw4_k<<<15552,256,0,stream>>>(qkvw + (size_t)l*1152*3456,
                projw + (size_t)l*1152*1152, fc1w + (size_t)l*1152*4608,
                fc2w + (size_t)l*4608*1152, wt);
        } else {
            tw_k<<<dim3(216,36),256,0,stream>>>(adaw + (size_t)l*1152*6912, 1152, 6912, wt);
            gemm2_k<2><<<dim3(5,54),256,0,stream>>>(siluc,1152, wt,1152, adab + (size_t)l*6912,
                nullptr, modb7, 6912, 516, 1152, nullptr, nullptr, 0, 0, 0);
        }
        ln_mod_k<<<4096,256,0,stream>>>(xbuf, mptr, 6912, 0, ybuf, 0);
        // qkv (all rows: K/V needed everywhere)
        if (!merged) tw_k<<<dim3(108,36),256,0,stream>>>(qkvw + (size_t)l*1152*3456, 1152, 3456, wt);
        gemm2_k<0><<<dim3(32,27),256,0,stream>>>(ybuf,1152, wt_qkv,1152, qkvb + (size_t)l*3456,
            qh, nullptr, 3456, 4096, 1152, nullptr, nullptr, 0, 0, 0);
        // attention: last layer only needs GEN-row queries (qb 4..7 = first 256 blocks)
        attn5_k<<<(last ? 256 : 512),512,0,stream>>>(qh, ybuf);
        // proj (+ gated residual into xbuf)
        if (!merged) tw_k<<<dim3(36,36),256,0,stream>>>(projw + (size_t)l*1152*1152, 1152, 1152, wt);
        gemm2_k<3><<<dim3(last ? 16 : 32, 9),256,0,stream>>>(ybuf,1152, wt_prj,1152,
            projb + (size_t)l*1152, nullptr, nullptr, 1152, 4096, 1152, xbuf, mptr, 6912, 2304, gmap);
        ln_mod_k<<<(last ? 2048 : 4096),256,0,stream>>>(xbuf, mptr, 6912, 3456, ybuf, gmap);
        // fc1 (gelu)
        if (!merged) tw_k<<<dim3(144,36),256,0,stream>>>(fc1w + (size_t)l*1152*4608, 1152, 4608, wt);
        gemm2_k<1><<<dim3(last ? 16 : 32, 36),256,0,stream>>>(ybuf,1152, wt_fc1,1152,
            fc1b + (size_t)l*4608, qh, nullptr, 4608, 4096, 1152, nullptr, nullptr, 0, 0, gmap);
        // fc2 (+ gated residual into xbuf)
        if (!merged) tw_k<<<dim3(36,144),256,0,stream>>>(fc2w + (size_t)l*4608*1152, 4608, 1152, wt);
        gemm2_k<3><<<dim3(last ? 16 : 32, 9),256,0,stream>>>(qh,4608, wt_fc2,4608,
            fc2b + (size_t)l*1152, nullptr, nullptr, 1152, 4096, 4608, xbuf, mptr, 6912, 5760, gmap);
    }
    // final adaLN + projection
    unsigned short* wfin = merged ? wtf : wt;
    tw_k<<<dim3(72,36),256,0,stream>>>(finaw, 1152, 2304, wfin);
    gemm2_k<2><<<dim3(5,18),256,0,stream>>>(siluc,1152, wfin,1152, finab,
        nullptr, modb7, 2304, 516, 1152, nullptr, nullptr, 0, 0, 0);
    final_k<<<256,256,0,stream>>>(xbuf, modb7, finw, finb, (float*)d_out);
}

// Round 14
// 2642.836 us; speedup vs baseline: 1.1268x; 1.0817x over previous
//
#include <hip/hip_runtime.h>

// ---------------- types & helpers ----------------
typedef float f32x4 __attribute__((ext_vector_type(4)));
typedef __bf16 bf16x8 __attribute__((ext_vector_type(8)));
typedef unsigned short us8 __attribute__((ext_vector_type(8)));

static __device__ __forceinline__ unsigned short f2bf(float f){
    unsigned int u = __builtin_bit_cast(unsigned int, f);
    u += 0x7fffu + ((u >> 16) & 1u);
    return (unsigned short)(u >> 16);
}
static __device__ __forceinline__ bf16x8 ldb8(const unsigned short* p){
    return __builtin_bit_cast(bf16x8, *(const us8*)p);
}
typedef __attribute__((address_space(1))) void gas_void;
typedef __attribute__((address_space(3))) void las_void;
static __device__ __forceinline__ void gload_lds16(const void* g, void* l){
    __builtin_amdgcn_global_load_lds((gas_void*)g, (las_void*)l, 16, 0, 0);
}
static __device__ __forceinline__ float siluf(float v){
    return v / (1.f + __expf(-v));
}

// ---------------- prep: silu(plug_c_ref) rows 0..511, zero pad rows 512..639 ----------------
__global__ __launch_bounds__(256) void silu_hist_k(const float* __restrict__ plug,
                                                   unsigned short* __restrict__ siluc){
    int i = blockIdx.x*256 + threadIdx.x;
    if (i < 512*1152){
        siluc[i] = f2bf(siluf(plug[i]));
    } else if (i < 640*1152){
        siluc[i] = 0;   // pad rows: safe A-tile overread for M=516 GEMMs
    }
}

// ---------------- timestep MLP stage 1 (split-K x4): hl = silu(emb @ t_w0 + b0) ----------------
__global__ __launch_bounds__(256) void cgen1_k(const float* __restrict__ noise,
    const float* __restrict__ t_w0, const float* __restrict__ t_b0,
    float* __restrict__ hl){
    __shared__ float emb[256];
    __shared__ float part[4][64];
    const int t = threadIdx.x;
    const int b = blockIdx.y;
    const int c = blockIdx.x*64 + (t & 63);
    const int kg = t >> 6;
    const float tv = noise[b];
    if (t < 128){
        float arg = tv * __expf(-0.07195578415606394f * (float)t);
        emb[t] = cosf(arg);
        emb[128 + t] = sinf(arg);
    }
    __syncthreads();
    float s = 0.f;
    #pragma unroll 4
    for (int j = kg*64; j < kg*64 + 64; j++) s += emb[j] * t_w0[j*1152 + c];
    part[kg][t & 63] = s;
    __syncthreads();
    if (t < 64){
        float v = part[0][t] + part[1][t] + part[2][t] + part[3][t] + t_b0[c];
        hl[b*1152 + c] = siluf(v);
    }
}

// ---------------- timestep MLP stage 2 (split-K x4): siluc[512+b] = silu(hl @ t_w2 + b2) ----------------
__global__ __launch_bounds__(256) void cgen2_k(const float* __restrict__ hl,
    const float* __restrict__ t_w2, const float* __restrict__ t_b2,
    unsigned short* __restrict__ siluc){
    __shared__ float h[1152];
    __shared__ float part[4][64];
    const int t = threadIdx.x;
    const int b = blockIdx.y;
    const int c = blockIdx.x*64 + (t & 63);
    const int kg = t >> 6;
    for (int j = t; j < 1152; j += 256) h[j] = hl[b*1152 + j];
    __syncthreads();
    float s = 0.f;
    #pragma unroll 4
    for (int j = kg*288; j < kg*288 + 288; j++) s += h[j] * t_w2[j*1152 + c];
    part[kg][t & 63] = s;
    __syncthreads();
    if (t < 64){
        float v = part[0][t] + part[1][t] + part[2][t] + part[3][t] + t_b2[c];
        siluc[(size_t)(512 + b)*1152 + c] = f2bf(siluf(v));
    }
}

// ---------------- prep: x0 = tile(concat(rawhist,x),36) + pos_embed ----------------
__global__ __launch_bounds__(256) void x0_k(const float* __restrict__ xg,
    const float* __restrict__ rh, const float* __restrict__ pe, float* __restrict__ x){
    int i4 = blockIdx.x*256 + threadIdx.x;          // float4 index
    if (i4 >= 1179648) return;                      // 4096*1152/4
    int m = i4 / 288;
    int c = (i4 - m*288) * 4;
    int pos = m & 1023, b = m >> 10;
    const float* src = (pos < 512) ? (rh + ((size_t)b*512 + pos)*32)
                                   : (xg + ((size_t)b*512 + (pos-512))*32);
    float4 sv = *(const float4*)(src + (c & 31));
    float4 pv = *(const float4*)(pe + (size_t)pos*1152 + c);
    float4 o; o.x = sv.x+pv.x; o.y = sv.y+pv.y; o.z = sv.z+pv.z; o.w = sv.w+pv.w;
    *(float4*)(x + (size_t)i4*4) = o;
}

// ---------------- 32x32 transpose-convert body ----------------
static __device__ __forceinline__ void tw32_body(const float* __restrict__ W, int Kd, int Nd,
                                                 unsigned short* __restrict__ Wt,
                                                 int n0, int k0, int t){
    __shared__ float tile[32][33];
    #pragma unroll
    for (int i = 0; i < 4; i++){
        int idx = t + 256*i;
        int kk = idx >> 5, nn = idx & 31;
        tile[kk][nn] = W[(size_t)(k0+kk)*Nd + n0+nn];
    }
    __syncthreads();
    #pragma unroll
    for (int i = 0; i < 4; i++){
        int idx = t + 256*i;
        int nn = idx >> 5, kk = idx & 31;
        Wt[(size_t)(n0+nn)*Kd + k0+kk] = f2bf(tile[kk][nn]);
    }
}

__global__ __launch_bounds__(256) void tw_k(const float* __restrict__ W, int Kd, int Nd,
                                            unsigned short* __restrict__ Wt){
    tw32_body(W, Kd, Nd, Wt, blockIdx.x*32, blockIdx.y*32, threadIdx.x);
}

// ---------------- all 7 layers' ada weights upfront: 7 x 216x36 = 54432 tiles ----------------
__global__ __launch_bounds__(256) void twada7_k(const float* __restrict__ adaw,
                                                unsigned short* __restrict__ wta){
    int bid = blockIdx.x;
    const int l = bid / 7776;
    int local = bid - l*7776;                       // 216 x 36 tiles of 32x32
    const float* W = adaw + (size_t)l*7962624ul;    // 1152x6912 f32
    unsigned short* Wt = wta + (size_t)l*7962624ul; // 6912x1152 bf16
    tw32_body(W, 1152, 6912, Wt, (local % 216)*32, (local / 216)*32, threadIdx.x);
}

// ---------------- per-layer transpose of qkv/proj/fc1/fc2 ----------------
// tiles: qkv 108x36=3888 | proj 36x36=1296 | fc1 144x36=5184 | fc2 36x144=5184  (= 15552)
__global__ __launch_bounds__(256) void tw4_k(const float* __restrict__ w1,
    const float* __restrict__ w2, const float* __restrict__ w3, const float* __restrict__ w4,
    unsigned short* __restrict__ wt){
    const int cum[4]  = {3888, 5184, 10368, 15552};
    const int kds[4]  = {1152, 1152, 1152, 4608};
    const int nds[4]  = {3456, 1152, 4608, 1152};
    const size_t dof[4] = {7962624ul, 11943936ul, 13271040ul, 18579456ul};
    int bid = blockIdx.x;
    int w = (bid < cum[1]) ? ((bid < cum[0]) ? 0 : 1) : ((bid < cum[2]) ? 2 : 3);
    int local = bid - (w ? cum[w-1] : 0);
    const float* W = (w==0)?w1:(w==1)?w2:(w==2)?w3:w4;
    const int Kd = kds[w], Nd = nds[w];
    const int ntx = Nd >> 5;
    tw32_body(W, Kd, Nd, wt + dof[w], (local % ntx)*32, (local / ntx)*32, threadIdx.x);
}

// ---------------- LN (no affine) + modulate -> bf16 ----------------
// genonly: grid 2048, rows b*1024 + 512 + p (GEN rows only)
__global__ __launch_bounds__(256) void ln_mod_k(const float* __restrict__ x,
    const float* __restrict__ modb, int mld, int ofs, unsigned short* __restrict__ y,
    int genonly){
    const int bx = blockIdx.x, t = threadIdx.x;
    const int m = genonly ? ((bx >> 9)*1024 + 512 + (bx & 511)) : bx;
    const int lane = t & 63, wv = t >> 6;
    const float* xr = x + (size_t)m*1152;
    float4 v0 = ((const float4*)xr)[t];
    float4 v1 = {0.f,0.f,0.f,0.f};
    bool h2 = (t < 32);
    if (h2) v1 = ((const float4*)xr)[256 + t];
    float s = v0.x+v0.y+v0.z+v0.w + v1.x+v1.y+v1.z+v1.w;
    float q = v0.x*v0.x+v0.y*v0.y+v0.z*v0.z+v0.w*v0.w
            + v1.x*v1.x+v1.y*v1.y+v1.z*v1.z+v1.w*v1.w;
    #pragma unroll
    for (int o = 32; o; o >>= 1){ s += __shfl_xor(s,o); q += __shfl_xor(q,o); }
    __shared__ float red[8];
    if (lane == 0){ red[wv] = s; red[4+wv] = q; }
    __syncthreads();
    s = red[0]+red[1]+red[2]+red[3];
    q = red[4]+red[5]+red[6]+red[7];
    const float mean = s * (1.f/1152.f);
    const float var  = q * (1.f/1152.f) - mean*mean;
    const float rstd = rsqrtf(var + 1e-6f);
    const int pos = m & 1023, bb = m >> 10;
    const int mrow = (pos < 512) ? pos : (512 + bb);
    const float* sh = modb + (size_t)mrow*mld + ofs;
    const float* sc = sh + 1152;
    {
        int c = t*4;
        float4 shv = *(const float4*)(sh + c);
        float4 scv = *(const float4*)(sc + c);
        ushort4 o4;
        o4.x = f2bf((v0.x-mean)*rstd*(1.f+scv.x) + shv.x);
        o4.y = f2bf((v0.y-mean)*rstd*(1.f+scv.y) + shv.y);
        o4.z = f2bf((v0.z-mean)*rstd*(1.f+scv.z) + shv.z);
        o4.w = f2bf((v0.w-mean)*rstd*(1.f+scv.w) + shv.w);
        *(ushort4*)(y + (size_t)m*1152 + c) = o4;
    }
    if (h2){
        int c = 1024 + t*4;
        float4 shv = *(const float4*)(sh + c);
        float4 scv = *(const float4*)(sc + c);
        ushort4 o4;
        o4.x = f2bf((v1.x-mean)*rstd*(1.f+scv.x) + shv.x);
        o4.y = f2bf((v1.y-mean)*rstd*(1.f+scv.y) + shv.y);
        o4.z = f2bf((v1.z-mean)*rstd*(1.f+scv.z) + shv.z);
        o4.w = f2bf((v1.w-mean)*rstd*(1.f+scv.w) + shv.w);
        *(ushort4*)(y + (size_t)m*1152 + c) = o4;
    }
}

// ---------------- GEMM (m97 structure): out = epi(A(bf16,MxK) @ Wt^T + bias) ----------------
// EPI: 0 = bf16 store, 1 = gelu->bf16, 2 = f32 store (guard row<M), 3 = x += gate*(v)
// genmap: M-tiles remapped to GEN rows: m-tile = batch*8 + 4 + (bx&3), bx in 0..15
template<int EPI>
__global__ __launch_bounds__(256,2)
void gemm2_k(const unsigned short* __restrict__ A, int lda,
             const unsigned short* __restrict__ B, int ldb,
             const float* __restrict__ bias,
             unsigned short* __restrict__ outb, float* __restrict__ outf, int ldo,
             int M, int K,
             float* __restrict__ xres,
             const float* __restrict__ modb, int mld, int gofs,
             int genmap){
    __shared__ unsigned short Alds[128*32];
    __shared__ unsigned short Blds[128*32];
    const int tid  = threadIdx.x;
    const int lane = tid & 63;
    const int wv   = tid >> 6;
    const int wr   = wv >> 1, wc = wv & 1;
    const int bx = blockIdx.x;
    const int m0 = (genmap ? ((bx >> 2)*8 + 4 + (bx & 3)) : bx) * 128;
    const int n0 = blockIdx.y * 128;

    const int r0 = (wv*2 + 0)*16 + (lane >> 2);
    const int r1 = (wv*2 + 1)*16 + (lane >> 2);
    const unsigned short* ag0 = A + (size_t)(m0 + r0)*lda + (lane & 3)*8;
    const unsigned short* ag1 = A + (size_t)(m0 + r1)*lda + (lane & 3)*8;
    const unsigned short* bg0 = B + (size_t)(n0 + r0)*ldb + (lane & 3)*8;
    const unsigned short* bg1 = B + (size_t)(n0 + r1)*ldb + (lane & 3)*8;
    unsigned short* al0 = &Alds[(wv*2 + 0)*512];
    unsigned short* al1 = &Alds[(wv*2 + 1)*512];
    unsigned short* bl0 = &Blds[(wv*2 + 0)*512];
    unsigned short* bl1 = &Blds[(wv*2 + 1)*512];

    f32x4 acc[4][4];
    #pragma unroll
    for (int i = 0; i < 4; i++)
        #pragma unroll
        for (int j = 0; j < 4; j++){ f32x4 z = {0.f,0.f,0.f,0.f}; acc[i][j] = z; }

    for (int ks = 0; ks < K; ks += 32){
        if (ks) __syncthreads();
        gload_lds16((const void*)ag0, (void*)al0);
        gload_lds16((const void*)ag1, (void*)al1);
        gload_lds16((const void*)bg0, (void*)bl0);
        gload_lds16((const void*)bg1, (void*)bl1);
        ag0 += 32; ag1 += 32; bg0 += 32; bg1 += 32;
        __syncthreads();
        bf16x8 af[4], bfm[4];
        #pragma unroll
        for (int mt = 0; mt < 4; mt++)
            af[mt] = ldb8(&Alds[(wr*64 + mt*16 + (lane&15))*32 + (lane>>4)*8]);
        #pragma unroll
        for (int nt = 0; nt < 4; nt++)
            bfm[nt] = ldb8(&Blds[(wc*64 + nt*16 + (lane&15))*32 + (lane>>4)*8]);
        #pragma unroll
        for (int mt = 0; mt < 4; mt++)
            #pragma unroll
            for (int nt = 0; nt < 4; nt++)
                acc[mt][nt] = __builtin_amdgcn_mfma_f32_16x16x32_bf16(af[mt], bfm[nt], acc[mt][nt], 0,0,0);
    }

    const int cb = n0 + wc*64;
    const int rb = m0 + wr*64;
    #pragma unroll
    for (int nt = 0; nt < 4; nt++){
        int col = cb + nt*16 + (lane & 15);
        float bn = bias[col];
        #pragma unroll
        for (int mt = 0; mt < 4; mt++){
            #pragma unroll
            for (int i = 0; i < 4; i++){
                int row = rb + mt*16 + (lane>>4)*4 + i;
                float v = acc[mt][nt][i] + bn;
                if (EPI == 0){
                    outb[(size_t)row*ldo + col] = f2bf(v);
                } else if (EPI == 1){
                    float z = 0.7978845608f*(v + 0.044715f*v*v*v);
                    float e = __expf(-2.f*fabsf(z));
                    float th = (1.f - e)/(1.f + e);
                    th = (z >= 0.f) ? th : -th;
                    outb[(size_t)row*ldo + col] = f2bf(0.5f*v*(1.f + th));
                } else if (EPI == 2){
                    if (row < M) outf[(size_t)row*ldo + col] = v;
                } else {
                    int pos = row & 1023, bb2 = row >> 10;
                    int mrow = (pos < 512) ? pos : (512 + bb2);
                    float g = modb[(size_t)mrow*mld + gofs + col];
                    xres[(size_t)row*1152 + col] += g * v;
                }
            }
        }
    }
}

// ---------------- GEMM v3: 64x128 tile, 256 thr, 2x2 waves of 32x64 — for narrow GEMMs ----
// EPI3 only (x += gate * (A@B^T + bias)). genmap: 64-row GEN tiles (bx>>3)*16 + 8 + (bx&7).
__global__ __launch_bounds__(256,2)
void gemm3_k(const unsigned short* __restrict__ A, int lda,
             const unsigned short* __restrict__ B, int ldb,
             const float* __restrict__ bias, int K,
             float* __restrict__ xres,
             const float* __restrict__ modb, int mld, int gofs,
             int genmap){
    __shared__ unsigned short Alds[64*32];     // 4 KB
    __shared__ unsigned short Blds[128*32];    // 8 KB
    const int tid  = threadIdx.x;
    const int lane = tid & 63;
    const int w    = tid >> 6;                 // 0..3
    const int wr   = w >> 1, wc = w & 1;       // 2x2 wave grid, 32x64 each
    const int bx = blockIdx.x;
    const int m0 = (genmap ? ((bx >> 3)*16 + 8 + (bx & 7)) : bx) * 64;
    const int n0 = blockIdx.y * 128;

    const int srow = w*16 + (lane >> 2);       // staging row within 64-slab
    const unsigned short* ag  = A + (size_t)(m0 + srow)*lda + (lane & 3)*8;
    const unsigned short* bg0 = B + (size_t)(n0 + srow)*ldb + (lane & 3)*8;
    const unsigned short* bg1 = B + (size_t)(n0 + 64 + srow)*ldb + (lane & 3)*8;
    unsigned short* al  = &Alds[(w*16)*32];
    unsigned short* bl0 = &Blds[(w*16)*32];
    unsigned short* bl1 = &Blds[(64 + w*16)*32];

    f32x4 acc[2][4];
    #pragma unroll
    for (int i = 0; i < 2; i++)
        #pragma unroll
        for (int j = 0; j < 4; j++){ f32x4 z = {0.f,0.f,0.f,0.f}; acc[i][j] = z; }

    for (int ks = 0; ks < K; ks += 32){
        if (ks) __syncthreads();
        gload_lds16((const void*)ag,  (void*)al);
        gload_lds16((const void*)bg0, (void*)bl0);
        gload_lds16((const void*)bg1, (void*)bl1);
        ag += 32; bg0 += 32; bg1 += 32;
        __syncthreads();
        bf16x8 af[2], bfm[4];
        #pragma unroll
        for (int mt = 0; mt < 2; mt++)
            af[mt] = ldb8(&Alds[(wr*32 + mt*16 + (lane&15))*32 + (lane>>4)*8]);
        #pragma unroll
        for (int nt = 0; nt < 4; nt++)
            bfm[nt] = ldb8(&Blds[(wc*64 + nt*16 + (lane&15))*32 + (lane>>4)*8]);
        #pragma unroll
        for (int mt = 0; mt < 2; mt++)
            #pragma unroll
            for (int nt = 0; nt < 4; nt++)
                acc[mt][nt] = __builtin_amdgcn_mfma_f32_16x16x32_bf16(af[mt], bfm[nt], acc[mt][nt], 0,0,0);
    }

    const int cb = n0 + wc*64;
    const int rb = m0 + wr*32;
    #pragma unroll
    for (int nt = 0; nt < 4; nt++){
        int col = cb + nt*16 + (lane & 15);
        float bn = bias[col];
        #pragma unroll
        for (int mt = 0; mt < 2; mt++){
            #pragma unroll
            for (int i = 0; i < 4; i++){
                int row = rb + mt*16 + (lane>>4)*4 + i;
                float v = acc[mt][nt][i] + bn;
                int pos = row & 1023, bb2 = row >> 10;
                int mrow = (pos < 512) ? pos : (512 + bb2);
                float g = modb[(size_t)mrow*mld + gofs + col];
                xres[(size_t)row*1152 + col] += g * v;
            }
        }
    }
}

// ---------------- batched ada GEMM with XCD panel swizzle ----------------
// grid 1920 x 1D. Panel p = z*54 + n (378 panels), m in 0..4.
// bid = (p%8) + 8*(m + 5*(p/8)): same-panel blocks 8 apart -> same XCD L2.
__global__ __launch_bounds__(256,2)
void gemm_ada_k(const unsigned short* __restrict__ A,
                const unsigned short* __restrict__ Wta,
                const float* __restrict__ adab,
                float* __restrict__ modb7){
    const int bid = blockIdx.x;
    const int r8 = bid & 7;
    const int t8 = bid >> 3;
    const int m  = t8 % 5;
    const int p  = (t8 / 5)*8 + r8;
    if (p >= 378) return;
    const int z = p / 54, n = p % 54;
    const unsigned short* B = Wta + (size_t)z*7962624ul;
    const float* bias = adab + (size_t)z*6912;
    float* outf = modb7 + (size_t)z*3566592ul;
    const int m0 = m * 128;
    const int n0 = n * 128;

    __shared__ unsigned short Alds[128*32];
    __shared__ unsigned short Blds[128*32];
    const int tid  = threadIdx.x;
    const int lane = tid & 63;
    const int wv   = tid >> 6;
    const int wr   = wv >> 1, wc = wv & 1;

    const int r0 = (wv*2 + 0)*16 + (lane >> 2);
    const int r1 = (wv*2 + 1)*16 + (lane >> 2);
    const unsigned short* ag0 = A + (size_t)(m0 + r0)*1152 + (lane & 3)*8;
    const unsigned short* ag1 = A + (size_t)(m0 + r1)*1152 + (lane & 3)*8;
    const unsigned short* bg0 = B + (size_t)(n0 + r0)*1152 + (lane & 3)*8;
    const unsigned short* bg1 = B + (size_t)(n0 + r1)*1152 + (lane & 3)*8;
    unsigned short* al0 = &Alds[(wv*2 + 0)*512];
    unsigned short* al1 = &Alds[(wv*2 + 1)*512];
    unsigned short* bl0 = &Blds[(wv*2 + 0)*512];
    unsigned short* bl1 = &Blds[(wv*2 + 1)*512];

    f32x4 acc[4][4];
    #pragma unroll
    for (int i = 0; i < 4; i++)
        #pragma unroll
        for (int j = 0; j < 4; j++){ f32x4 zv = {0.f,0.f,0.f,0.f}; acc[i][j] = zv; }

    for (int ks = 0; ks < 1152; ks += 32){
        if (ks) __syncthreads();
        gload_lds16((const void*)ag0, (void*)al0);
        gload_lds16((const void*)ag1, (void*)al1);
        gload_lds16((const void*)bg0, (void*)bl0);
        gload_lds16((const void*)bg1, (void*)bl1);
        ag0 += 32; ag1 += 32; bg0 += 32; bg1 += 32;
        __syncthreads();
        bf16x8 af[4], bfm[4];
        #pragma unroll
        for (int mt = 0; mt < 4; mt++)
            af[mt] = ldb8(&Alds[(wr*64 + mt*16 + (lane&15))*32 + (lane>>4)*8]);
        #pragma unroll
        for (int nt = 0; nt < 4; nt++)
            bfm[nt] = ldb8(&Blds[(wc*64 + nt*16 + (lane&15))*32 + (lane>>4)*8]);
        #pragma unroll
        for (int mt = 0; mt < 4; mt++)
            #pragma unroll
            for (int nt = 0; nt < 4; nt++)
                acc[mt][nt] = __builtin_amdgcn_mfma_f32_16x16x32_bf16(af[mt], bfm[nt], acc[mt][nt], 0,0,0);
    }

    const int cb = n0 + wc*64;
    const int rb = m0 + wr*64;
    #pragma unroll
    for (int nt = 0; nt < 4; nt++){
        int col = cb + nt*16 + (lane & 15);
        float bn = bias[col];
        #pragma unroll
        for (int mt = 0; mt < 4; mt++){
            #pragma unroll
            for (int i = 0; i < 4; i++){
                int row = rb + mt*16 + (lane>>4)*4 + i;
                float v = acc[mt][nt][i] + bn;
                if (row < 516) outf[(size_t)row*6912 + col] = v;
            }
        }
    }
}

// ---------------- flash attention v5: 8 waves x 16 q rows, 128-kv super-tiles ----------------
__global__ __launch_bounds__(512)
void attn5_k(const unsigned short* __restrict__ qkv, unsigned short* __restrict__ o){
    __shared__ unsigned short Kl[128*104];    // 26.0 KB
    __shared__ unsigned short Vt[80*136];     // 21.25 KB  [d][kv], row 72 = ones
    __shared__ unsigned short Pl[8][16*40];   // 10 KB
    const int tid  = threadIdx.x;
    const int lane = tid & 63;
    const int w    = tid >> 6;
    const int bid  = blockIdx.x;
    const int qb   = 7 - (bid >> 6);          // heavy blocks first; 256-block launch -> qb 4..7
    const int bh   = bid & 63;
    const int h = bh & 15, b = bh >> 4;
    const size_t base = (size_t)b*1024*3456;
    const int qcol = h*72, kcol = 1152 + h*72, vcol = 2304 + h*72;

    for (int idx = tid; idx < 2048; idx += 512){
        int r = idx >> 4, cw = idx & 15;
        ((unsigned int*)Kl)[r*52 + 36 + cw] = 0u;
    }
    if (tid < 544){
        int r = tid/68;
        ((unsigned int*)Vt)[(72+r)*68 + (tid - r*68)] = (r == 0) ? 0x3F803F80u : 0u;
    }

    bf16x8 qreg[3];
    const int q0 = qb*128 + w*16;
    {
        bf16x8 z8 = {};
        const unsigned short* qp = qkv + base + (size_t)(q0 + (lane&15))*3456 + qcol;
        const int off = (lane>>4)*8;
        qreg[0] = ldb8(qp + off);
        qreg[1] = ldb8(qp + 32 + off);
        qreg[2] = (lane < 16) ? ldb8(qp + 64) : z8;
    }

    float mi[4];
    f32x4 oa[5];
    #pragma unroll
    for (int i = 0; i < 4; i++) mi[i] = -INFINITY;
    #pragma unroll
    for (int d = 0; d < 5; d++){ f32x4 z = {0.f,0.f,0.f,0.f}; oa[d] = z; }

    const int nS = qb + 1;
    const float qsc = 0.11785113019775793f;

    for (int S = 0; S < nS; S++){
        const int kvS = S*128;
        __syncthreads();
        for (int ch = tid; ch < 2304; ch += 512){
            int r = ch/18, d4 = (ch - r*18)*4;
            *(ushort4*)&Kl[r*104 + d4] =
                *(const ushort4*)(qkv + base + (size_t)(kvS + r)*3456 + kcol + d4);
        }
        for (int ch = tid; ch < 1152; ch += 512){
            int rp = ch & 63, d4 = (ch >> 6)*4;
            const unsigned short* vp = qkv + base + (size_t)(kvS + 2*rp)*3456 + vcol + d4;
            ushort4 v0 = *(const ushort4*)vp;
            ushort4 v1 = *(const ushort4*)(vp + 3456);
            *(ushort2*)&Vt[(d4+0)*136 + 2*rp] = make_ushort2(v0.x, v1.x);
            *(ushort2*)&Vt[(d4+1)*136 + 2*rp] = make_ushort2(v0.y, v1.y);
            *(ushort2*)&Vt[(d4+2)*136 + 2*rp] = make_ushort2(v0.z, v1.z);
            *(ushort2*)&Vt[(d4+3)*136 + 2*rp] = make_ushort2(v0.w, v1.w);
        }
        __syncthreads();

        for (int sub = 0; sub < 4; sub++){
            const int kvb = kvS + sub*32;
            if (kvb > q0 + 15) break;
            f32x4 s0 = {0.f,0.f,0.f,0.f}, s1 = {0.f,0.f,0.f,0.f};
            __builtin_amdgcn_s_setprio(1);
            #pragma unroll
            for (int st = 0; st < 3; st++){
                bf16x8 k0 = ldb8(&Kl[(sub*32 + (lane&15))*104 + (lane>>4)*8 + st*32]);
                bf16x8 k1 = ldb8(&Kl[(sub*32 + 16 + (lane&15))*104 + (lane>>4)*8 + st*32]);
                s0 = __builtin_amdgcn_mfma_f32_16x16x32_bf16(qreg[st], k0, s0, 0,0,0);
                s1 = __builtin_amdgcn_mfma_f32_16x16x32_bf16(qreg[st], k1, s1, 0,0,0);
            }
            __builtin_amdgcn_s_setprio(0);
            const bool domask = (kvb + 31 > q0);
            float p0[4], p1[4];
            #pragma unroll
            for (int i = 0; i < 4; i++){
                float a = s0[i]*qsc, c = s1[i]*qsc;
                if (domask){
                    int r = q0 + (lane>>4)*4 + i;
                    if (kvb + (lane&15) > r) a = -1e30f;
                    if (kvb + 16 + (lane&15) > r) c = -1e30f;
                }
                float pm = fmaxf(a, c);
                #pragma unroll
                for (int off = 1; off < 16; off <<= 1) pm = fmaxf(pm, __shfl_xor(pm, off));
                float nm = fmaxf(mi[i], pm);
                float f = __expf(mi[i] - nm);
                mi[i] = nm;
                p0[i] = __expf(a - nm);
                p1[i] = __expf(c - nm);
                #pragma unroll
                for (int d = 0; d < 5; d++) oa[d][i] *= f;
            }
            unsigned short* Pw = Pl[w];
            #pragma unroll
            for (int i = 0; i < 4; i++){
                int r = (lane>>4)*4 + i;
                Pw[r*40 + (lane&15)]      = f2bf(p0[i]);
                Pw[r*40 + 16 + (lane&15)] = f2bf(p1[i]);
            }
            bf16x8 pa = ldb8(&Pw[(lane&15)*40 + (lane>>4)*8]);
            __builtin_amdgcn_s_setprio(1);
            #pragma unroll
            for (int d = 0; d < 5; d++){
                bf16x8 bv = ldb8(&Vt[(d*16 + (lane&15))*136 + sub*32 + (lane>>4)*8]);
                oa[d] = __builtin_amdgcn_mfma_f32_16x16x32_bf16(pa, bv, oa[d], 0,0,0);
            }
            __builtin_amdgcn_s_setprio(0);
        }
    }
    #pragma unroll
    for (int i = 0; i < 4; i++){
        float li = __shfl(oa[4][i], (lane & 48) | 8);
        float inv = 1.f / li;
        size_t row = (size_t)b*1024 + q0 + (lane>>4)*4 + i;
        #pragma unroll
        for (int d = 0; d < 5; d++){
            int c = d*16 + (lane & 15);
            if (c < 72) o[row*1152 + h*72 + c] = f2bf(oa[d][i]*inv);
        }
    }
}

// ---------------- final: out = modulate(x, sh, sc) @ fin_w + fin_b (GEN rows) ----------------
__global__ __launch_bounds__(256) void final_k(const float* __restrict__ x,
    const float* __restrict__ modf, const float* __restrict__ finw,
    const float* __restrict__ finb, float* __restrict__ outp){
    __shared__ float yl[1152];
    __shared__ float ps[8][32];
    const int t = threadIdx.x;
    for (int r = 0; r < 8; r++){
        int gr = blockIdx.x*8 + r;
        int b = gr >> 9, p = gr & 511;
        size_t m = (size_t)b*1024 + 512 + p;
        int mrow = 512 + b;
        const float* xr = x + m*1152;
        const float* md = modf + (size_t)mrow*2304;
        for (int c = t; c < 1152; c += 256)
            yl[c] = xr[c]*(1.f + md[1152 + c]) + md[c];
        __syncthreads();
        int j = t & 31, g = t >> 5;
        float s = 0.f;
        for (int c = g*144; c < g*144 + 144; c++) s += yl[c]*finw[c*32 + j];
        ps[g][j] = s;
        __syncthreads();
        if (t < 32){
            float acc = finb[j];
            #pragma unroll
            for (int gg = 0; gg < 8; gg++) acc += ps[gg][j];
            outp[((size_t)b*512 + p)*32 + j] = acc;
        }
        __syncthreads();
    }
}

// ---------------- host launch ----------------
extern "C" void kernel_launch(void* const* d_in, const int* in_sizes, int n_in,
                              void* d_out, int out_size, void* d_ws, size_t ws_size,
                              hipStream_t stream){
    const float* xin   = (const float*)d_in[0];
    const float* noise = (const float*)d_in[1];
    const float* rawh  = (const float*)d_in[2];
    const float* pose  = (const float*)d_in[4];
    const float* plug  = (const float*)d_in[5];
    const float* t_w0  = (const float*)d_in[6];
    const float* t_b0  = (const float*)d_in[7];
    const float* t_w2  = (const float*)d_in[8];
    const float* t_b2  = (const float*)d_in[9];
    const float* qkvw  = (const float*)d_in[10];
    const float* qkvb  = (const float*)d_in[11];
    const float* projw = (const float*)d_in[12];
    const float* projb = (const float*)d_in[13];
    const float* fc1w  = (const float*)d_in[14];
    const float* fc1b  = (const float*)d_in[15];
    const float* fc2w  = (const float*)d_in[16];
    const float* fc2b  = (const float*)d_in[17];
    const float* adaw  = (const float*)d_in[18];
    const float* adab  = (const float*)d_in[19];
    const float* finaw = (const float*)d_in[20];
    const float* finab = (const float*)d_in[21];
    const float* finw  = (const float*)d_in[22];
    const float* finb  = (const float*)d_in[23];

    char* ws = (char*)d_ws;
    float*          xbuf  = (float*)(ws + 0);                      // 4096x1152 f32   (18.87 MB)
    unsigned short* ybuf  = (unsigned short*)(ws + 18874368);      // 4096x1152 bf16  (9.44 MB)
    unsigned short* qh    = (unsigned short*)(ws + 28311552);      // 4096x4608 bf16  (37.75 MB)
    unsigned short* siluc = (unsigned short*)(ws + 66060288);      // 640x1152 bf16   (1.47 MB)
    float*          modb7 = (float*)(ws + 67534848);               // 7x516x6912 f32  (99.86 MB)
    unsigned short* wt    = (unsigned short*)(ws + 167399424);     // per-layer slab  (47.78 MB)
    unsigned short* wta   = (unsigned short*)(ws + 215175168);     // 7x6912x1152 bf16 (111.48 MB)
    unsigned short* wtf   = (unsigned short*)(ws + 326651904);     // final ada       (5.31 MB)
    float*          hl    = (float*)qh;

    const bool merged = (ws_size >= 331960320ul);

    silu_hist_k<<<2880,256,0,stream>>>(plug, siluc);
    cgen1_k<<<dim3(18,4),256,0,stream>>>(noise, t_w0, t_b0, hl);
    cgen2_k<<<dim3(18,4),256,0,stream>>>(hl, t_w2, t_b2, siluc);
    x0_k<<<4608,256,0,stream>>>(xin, rawh, pose, xbuf);

    if (merged){
        twada7_k<<<54432,256,0,stream>>>(adaw, wta);
        gemm_ada_k<<<1920,256,0,stream>>>(siluc, wta, adab, modb7);
    }

    unsigned short* wt_qkv = merged ? wt +  7962624 : wt;
    unsigned short* wt_prj = merged ? wt + 11943936 : wt;
    unsigned short* wt_fc1 = merged ? wt + 13271040 : wt;
    unsigned short* wt_fc2 = merged ? wt + 18579456 : wt;

    for (int l = 0; l < 7; l++){
        const bool last = (l == 6);
        const int gmap = last ? 1 : 0;
        float* mptr = merged ? modb7 + (size_t)l*3566592ul : modb7;
        if (merged){
            tw4_k<<<15552,256,0,stream>>>(qkvw + (size_t)l*1152*3456,
                projw + (size_t)l*1152*1152, fc1w + (size_t)l*1152*4608,
                fc2w + (size_t)l*4608*1152, wt);
        } else {
            tw_k<<<dim3(216,36),256,0,stream>>>(adaw + (size_t)l*1152*6912, 1152, 6912, wt);
            gemm2_k<2><<<dim3(5,54),256,0,stream>>>(siluc,1152, wt,1152, adab + (size_t)l*6912,
                nullptr, modb7, 6912, 516, 1152, nullptr, nullptr, 0, 0, 0);
        }
        ln_mod_k<<<4096,256,0,stream>>>(xbuf, mptr, 6912, 0, ybuf, 0);
        // qkv (all rows: K/V needed everywhere)
        if (!merged) tw_k<<<dim3(108,36),256,0,stream>>>(qkvw + (size_t)l*1152*3456, 1152, 3456, wt);
        gemm2_k<0><<<dim3(32,27),256,0,stream>>>(ybuf,1152, wt_qkv,1152, qkvb + (size_t)l*3456,
            qh, nullptr, 3456, 4096, 1152, nullptr, nullptr, 0, 0, 0);
        // attention: last layer only needs GEN-row queries (qb 4..7 = first 256 blocks)
        attn5_k<<<(last ? 256 : 512),512,0,stream>>>(qh, ybuf);
        // proj (+ gated residual into xbuf) — 64-row tiles for occupancy
        if (!merged) tw_k<<<dim3(36,36),256,0,stream>>>(projw + (size_t)l*1152*1152, 1152, 1152, wt);
        gemm3_k<<<dim3(last ? 32 : 64, 9),256,0,stream>>>(ybuf,1152, wt_prj,1152,
            projb + (size_t)l*1152, 1152, xbuf, mptr, 6912, 2304, gmap);
        ln_mod_k<<<(last ? 2048 : 4096),256,0,stream>>>(xbuf, mptr, 6912, 3456, ybuf, gmap);
        // fc1 (gelu)
        if (!merged) tw_k<<<dim3(144,36),256,0,stream>>>(fc1w + (size_t)l*1152*4608, 1152, 4608, wt);
        gemm2_k<1><<<dim3(last ? 16 : 32, 36),256,0,stream>>>(ybuf,1152, wt_fc1,1152,
            fc1b + (size_t)l*4608, qh, nullptr, 4608, 4096, 1152, nullptr, nullptr, 0, 0, gmap);
        // fc2 (+ gated residual into xbuf) — 64-row tiles for occupancy
        if (!merged) tw_k<<<dim3(36,144),256,0,stream>>>(fc2w + (size_t)l*4608*1152, 4608, 1152, wt);
        gemm3_k<<<dim3(last ? 32 : 64, 9),256,0,stream>>>(qh,4608, wt_fc2,4608,
            fc2b + (size_t)l*1152, 4608, xbuf, mptr, 6912, 5760, gmap);
    }
    // final adaLN + projection
    unsigned short* wfin = merged ? wtf : wt;
    tw_k<<<dim3(72,36),256,0,stream>>>(finaw, 1152, 2304, wfin);
    gemm2_k<2><<<dim3(5,18),256,0,stream>>>(siluc,1152, wfin,1152, finab,
        nullptr, modb7, 2304, 516, 1152, nullptr, nullptr, 0, 0, 0);
    final_k<<<256,256,0,stream>>>(xbuf, modb7, finw, finb, (float*)d_out);
}